// Round 5
// baseline (436.360 us; speedup 1.0000x reference)
//
#include <hip/hip_runtime.h>

typedef __attribute__((ext_vector_type(8))) short short8;
typedef __attribute__((ext_vector_type(4))) short short4v;
typedef __attribute__((ext_vector_type(4))) float floatx4;

#define MFMA_BF16 __builtin_amdgcn_mfma_f32_16x16x32_bf16
#define LOG2E 1.44269504088896340736f

// K=16 bf16 MFMA (v_mfma_f32_16x16x16_bf16, A/B = 4 bf16 per lane).
// Guarded so the HIP host pass never parses the target builtin.
__device__ inline floatx4 MFMA16(short4v a, short4v b, floatx4 c){
#if defined(__HIP_DEVICE_COMPILE__)
  return __builtin_amdgcn_mfma_f32_16x16x16bf16_1k(a, b, c, 0, 0, 0);
#else
  return c;
#endif
}

// async global->LDS 16B (dwordx4). LDS dest must be wave-linear (base + lane*16).
__device__ inline void gll16(const unsigned short* g, unsigned short* l){
#if defined(__HIP_DEVICE_COMPILE__)
  __builtin_amdgcn_global_load_lds(
      (const __attribute__((address_space(1))) unsigned int*)g,
      (__attribute__((address_space(3))) unsigned int*)l, 16, 0, 0);
#else
  (void)g; (void)l;
#endif
}

__device__ inline unsigned short f2bf(float x){
  unsigned int u = __float_as_uint(x);
  u += 0x7fffu + ((u >> 16) & 1u);
  return (unsigned short)(u >> 16);
}
// truncating bf16 pair pack: (hi<<16)|lo, 1 instr
__device__ inline unsigned pack_bf(float lo, float hi){
  return __builtin_amdgcn_perm(__float_as_uint(hi), __float_as_uint(lo), 0x07060302u);
}

__device__ inline float wave_sum(float v){
  #pragma unroll
  for(int m=32;m>=1;m>>=1) v += __shfl_xor(v,m);
  return v;
}

// ---------------- GroupNorm1 (stats+apply+transpose). x:(BT,C,HW) -> xs:(BT,HW,C)
__global__ __launch_bounds__(256) void gn1_kernel(const float* __restrict__ x,
    const float* __restrict__ w, const float* __restrict__ b, float* __restrict__ xs){
  int g = blockIdx.x, bt = blockIdx.y, tid = threadIdx.x;
  const float* xp = x + ((size_t)bt*512 + g*16)*1024;
  float s=0.f, s2=0.f;
  #pragma unroll
  for(int it=0; it<16; ++it){
    float4 v = *(const float4*)(xp + it*1024 + tid*4);
    s  += v.x+v.y+v.z+v.w;
    s2 += v.x*v.x+v.y*v.y+v.z*v.z+v.w*v.w;
  }
  __shared__ float red[8];
  s = wave_sum(s); s2 = wave_sum(s2);
  int wid = tid>>6;
  if((tid&63)==0){ red[wid*2]=s; red[wid*2+1]=s2; }
  __syncthreads();
  s  = red[0]+red[2]+red[4]+red[6];
  s2 = red[1]+red[3]+red[5]+red[7];
  float mean = s * (1.f/16384.f);
  float var  = s2 * (1.f/16384.f) - mean*mean;
  float rinv = rsqrtf(var + 1e-5f);
  int c = tid & 15, h0 = tid >> 4;
  float sc = w[g*16+c]*rinv;
  float sh = b[g*16+c] - mean*sc;
  const float* xcol = xp + (size_t)c*1024;
  float* op = xs + (size_t)bt*1024*512 + g*16 + c;
  #pragma unroll 4
  for(int it=0; it<64; ++it){
    int hw = h0 + it*16;
    op[(size_t)hw*512] = xcol[hw]*sc + sh;
  }
}

// ---------------- Dual LayerNorm per row: vn (f32+bf16) with lnv params, lnl (bf16)
__global__ __launch_bounds__(256) void ln_dual_kernel(const float* __restrict__ xs,
    const float* __restrict__ lvw, const float* __restrict__ lvb,
    const float* __restrict__ llw, const float* __restrict__ llb,
    float* __restrict__ vn, unsigned short* __restrict__ vnb, unsigned short* __restrict__ lnlb){
  int wid = threadIdx.x>>6, l = threadIdx.x&63;
  size_t row = (size_t)blockIdx.x*4 + wid;
  const float* xp = xs + row*512;
  float4 a = *(const float4*)(xp + l*4);
  float4 c = *(const float4*)(xp + 256 + l*4);
  float s  = a.x+a.y+a.z+a.w + c.x+c.y+c.z+c.w;
  float s2 = a.x*a.x+a.y*a.y+a.z*a.z+a.w*a.w + c.x*c.x+c.y*c.y+c.z*c.z+c.w*c.w;
  s = wave_sum(s); s2 = wave_sum(s2);
  float mean = s*(1.f/512.f);
  float rinv = rsqrtf(s2*(1.f/512.f) - mean*mean + 1e-5f);
  int c0 = l*4, c1 = 256 + l*4;
  float y[8] = {(a.x-mean)*rinv,(a.y-mean)*rinv,(a.z-mean)*rinv,(a.w-mean)*rinv,
                (c.x-mean)*rinv,(c.y-mean)*rinv,(c.z-mean)*rinv,(c.w-mean)*rinv};
  float4 o0, o1;
  o0.x=y[0]*lvw[c0+0]+lvb[c0+0]; o0.y=y[1]*lvw[c0+1]+lvb[c0+1];
  o0.z=y[2]*lvw[c0+2]+lvb[c0+2]; o0.w=y[3]*lvw[c0+3]+lvb[c0+3];
  o1.x=y[4]*lvw[c1+0]+lvb[c1+0]; o1.y=y[5]*lvw[c1+1]+lvb[c1+1];
  o1.z=y[6]*lvw[c1+2]+lvb[c1+2]; o1.w=y[7]*lvw[c1+3]+lvb[c1+3];
  *(float4*)(vn + row*512 + c0) = o0;
  *(float4*)(vn + row*512 + c1) = o1;
  ushort4 h;
  h.x=f2bf(o0.x); h.y=f2bf(o0.y); h.z=f2bf(o0.z); h.w=f2bf(o0.w);
  *(ushort4*)(vnb + row*512 + c0) = h;
  h.x=f2bf(o1.x); h.y=f2bf(o1.y); h.z=f2bf(o1.z); h.w=f2bf(o1.w);
  *(ushort4*)(vnb + row*512 + c1) = h;
  h.x=f2bf(y[0]*llw[c0+0]+llb[c0+0]); h.y=f2bf(y[1]*llw[c0+1]+llb[c0+1]);
  h.z=f2bf(y[2]*llw[c0+2]+llb[c0+2]); h.w=f2bf(y[3]*llw[c0+3]+llb[c0+3]);
  *(ushort4*)(lnlb + row*512 + c0) = h;
  h.x=f2bf(y[4]*llw[c1+0]+llb[c1+0]); h.y=f2bf(y[5]*llw[c1+1]+llb[c1+1]);
  h.z=f2bf(y[6]*llw[c1+2]+llb[c1+2]); h.w=f2bf(y[7]*llw[c1+3]+llb[c1+3]);
  *(ushort4*)(lnlb + row*512 + c1) = h;
}

// ---------------- fused GN2-apply + LayerNorm (ca_lnv) -> vn2 f32 + bf16
// st holds RAW [sum, sum2] per (bt,g) accumulated by the MODE1 GEMM epilogue.
__global__ __launch_bounds__(256) void gn2ln_kernel(const float* __restrict__ xs2, const float* __restrict__ st,
    const float* __restrict__ gw, const float* __restrict__ gb,
    const float* __restrict__ lw, const float* __restrict__ lb,
    float* __restrict__ vn2, unsigned short* __restrict__ vn2b){
  int wid = threadIdx.x>>6, l = threadIdx.x&63;
  size_t row = (size_t)blockIdx.x*4 + wid;
  int bt = (int)(row >> 10);
  const float* xp = xs2 + row*512;
  float4 a = *(const float4*)(xp + l*4);
  float4 c = *(const float4*)(xp + 256 + l*4);
  int c0 = l*4, c1 = 256 + l*4;
  int g0 = c0>>4, g1 = c1>>4;
  float sm0 = st[(bt*32+g0)*2], sq0 = st[(bt*32+g0)*2+1];
  float sm1 = st[(bt*32+g1)*2], sq1 = st[(bt*32+g1)*2+1];
  float m0 = sm0*(1.f/16384.f);
  float r0 = rsqrtf(sq0*(1.f/16384.f) - m0*m0 + 1e-5f);
  float m1 = sm1*(1.f/16384.f);
  float r1 = rsqrtf(sq1*(1.f/16384.f) - m1*m1 + 1e-5f);
  float y[8];
  y[0]=(a.x-m0)*r0*gw[c0+0]+gb[c0+0]; y[1]=(a.y-m0)*r0*gw[c0+1]+gb[c0+1];
  y[2]=(a.z-m0)*r0*gw[c0+2]+gb[c0+2]; y[3]=(a.w-m0)*r0*gw[c0+3]+gb[c0+3];
  y[4]=(c.x-m1)*r1*gw[c1+0]+gb[c1+0]; y[5]=(c.y-m1)*r1*gw[c1+1]+gb[c1+1];
  y[6]=(c.z-m1)*r1*gw[c1+2]+gb[c1+2]; y[7]=(c.w-m1)*r1*gw[c1+3]+gb[c1+3];
  float s=0.f, s2=0.f;
  #pragma unroll
  for(int i=0;i<8;++i){ s += y[i]; s2 += y[i]*y[i]; }
  s = wave_sum(s); s2 = wave_sum(s2);
  float mean = s*(1.f/512.f);
  float rinv = rsqrtf(s2*(1.f/512.f) - mean*mean + 1e-5f);
  float4 o0, o1;
  o0.x=(y[0]-mean)*rinv*lw[c0+0]+lb[c0+0]; o0.y=(y[1]-mean)*rinv*lw[c0+1]+lb[c0+1];
  o0.z=(y[2]-mean)*rinv*lw[c0+2]+lb[c0+2]; o0.w=(y[3]-mean)*rinv*lw[c0+3]+lb[c0+3];
  o1.x=(y[4]-mean)*rinv*lw[c1+0]+lb[c1+0]; o1.y=(y[5]-mean)*rinv*lw[c1+1]+lb[c1+1];
  o1.z=(y[6]-mean)*rinv*lw[c1+2]+lb[c1+2]; o1.w=(y[7]-mean)*rinv*lw[c1+3]+lb[c1+3];
  *(float4*)(vn2 + row*512 + c0) = o0;
  *(float4*)(vn2 + row*512 + c1) = o1;
  ushort4 h;
  h.x=f2bf(o0.x); h.y=f2bf(o0.y); h.z=f2bf(o0.z); h.w=f2bf(o0.w);
  *(ushort4*)(vn2b + row*512 + c0) = h;
  h.x=f2bf(o1.x); h.y=f2bf(o1.y); h.z=f2bf(o1.z); h.w=f2bf(o1.w);
  *(ushort4*)(vn2b + row*512 + c1) = h;
}

// ---------------- context LayerNorm (ca_lnl) -> bf16, 154 rows
__global__ __launch_bounds__(256) void ctxln_kernel(const float* __restrict__ ctx,
    const float* __restrict__ lw, const float* __restrict__ lb, unsigned short* __restrict__ out){
  int wid = threadIdx.x>>6, l = threadIdx.x&63;
  int row = blockIdx.x*4 + wid;
  if(row >= 154) return;
  const float* xp = ctx + (size_t)row*512;
  float4 a = *(const float4*)(xp + l*4);
  float4 c = *(const float4*)(xp + 256 + l*4);
  float s  = a.x+a.y+a.z+a.w + c.x+c.y+c.z+c.w;
  float s2 = a.x*a.x+a.y*a.y+a.z*a.z+a.w*a.w + c.x*c.x+c.y*c.y+c.z*c.z+c.w*c.w;
  s = wave_sum(s); s2 = wave_sum(s2);
  float mean = s*(1.f/512.f);
  float rinv = rsqrtf(s2*(1.f/512.f) - mean*mean + 1e-5f);
  int c0 = l*4, c1 = 256 + l*4;
  ushort4 h;
  h.x=f2bf((a.x-mean)*rinv*lw[c0+0]+lb[c0+0]); h.y=f2bf((a.y-mean)*rinv*lw[c0+1]+lb[c0+1]);
  h.z=f2bf((a.z-mean)*rinv*lw[c0+2]+lb[c0+2]); h.w=f2bf((a.w-mean)*rinv*lw[c0+3]+lb[c0+3]);
  *(ushort4*)(out + (size_t)row*512 + c0) = h;
  h.x=f2bf((c.x-mean)*rinv*lw[c1+0]+lb[c1+0]); h.y=f2bf((c.y-mean)*rinv*lw[c1+1]+lb[c1+1]);
  h.z=f2bf((c.z-mean)*rinv*lw[c1+2]+lb[c1+2]); h.w=f2bf((c.w-mean)*rinv*lw[c1+3]+lb[c1+3]);
  *(ushort4*)(out + (size_t)row*512 + c1) = h;
}

// ---------------- weight fp32 -> bf16 (8 weights of 512x512)
__global__ __launch_bounds__(256) void cvtw_kernel(const float* s0, const float* s1, const float* s2,
    const float* s3, const float* s4, const float* s5, const float* s6, const float* s7,
    unsigned short* __restrict__ dst){
  const float* srcs[8] = {s0,s1,s2,s3,s4,s5,s6,s7};
  int w = blockIdx.y;
  const float* src = srcs[w];
  int i = (blockIdx.x*256 + threadIdx.x)*4;
  float4 v = *(const float4*)(src + i);
  ushort4 h; h.x=f2bf(v.x); h.y=f2bf(v.y); h.z=f2bf(v.z); h.w=f2bf(v.w);
  *(ushort4*)(dst + (size_t)w*262144 + i) = h;
}

// ---------------- bf16 MFMA GEMM v3 (2-phase pipelined): block tile 128m x 128n, BK=64,
// DOUBLE-buffered LDS, counted vmcnt(8) + raw s_barrier so next-tile global_load_lds
// stays in flight across the barrier (T3-minimum + T4). XOR-swizzled source + ds_read.
// MODE 0: outb = bf16((acc+bias)*scale)                       [natural]
// MODE 1: outf = r1 + r2 + gamma*(acc+bias); group sums -> (float*)outb via atomics
// MODE 2: outf[bt,c,hw] = r1 + gamma*(acc+bias)               [transposed f32]
// MODE 3: outb transposed bf16: VT[(m>>10)*512+col][m&1023]
// MODE 4: outb = V2T[(cb*512+col)*128 + key], cb=m>=77,key=m-77cb (M=154)
template<int MODE>
__global__ __launch_bounds__(256) void gemm128_kernel(const unsigned short* __restrict__ A,
    const unsigned short* __restrict__ W, const float* __restrict__ bias, int M, float scale,
    unsigned short* __restrict__ outb, float* __restrict__ outf,
    const float* __restrict__ r1, const float* __restrict__ r2, const float* __restrict__ gamma){
  __shared__ unsigned short Asl[2][128*64];   // [buf][row][k] 16KB each, kg XOR-swizzled by row&7
  __shared__ unsigned short Wsl[2][128*64];
  int tid = threadIdx.x, l = tid&63, wid = tid>>6, quad = l>>4, ln16 = l&15;
  int wr = wid>>1, wc = wid&1;
  int m0 = blockIdx.x*128, n0 = blockIdx.y*128;
  // staging: 4 insts per matrix; slot = i*256+tid; row=slot>>3, kg=slot&7 (16B units)
  // LDS dest linear (wave-contiguous); global source kg pre-swizzled: kg ^ (row&7)
  const unsigned short* Ag[4];
  const unsigned short* Wg[4];
  unsigned short* Al[4];
  unsigned short* Wl[4];
  #pragma unroll
  for(int i=0;i<4;++i){
    int s = i*256 + tid;
    int row = s>>3, kg = s&7;
    int kgs = kg ^ (row&7);
    int ar = m0+row; if(ar > M-1) ar = M-1;
    Ag[i] = A + (size_t)ar*512 + kgs*8;
    Wg[i] = W + (size_t)(n0+row)*512 + kgs*8;
    Al[i] = &Asl[0][0] + row*64 + kg*8;
    Wl[i] = &Wsl[0][0] + row*64 + kg*8;
  }
  floatx4 acc[4][4];
  #pragma unroll
  for(int mf=0;mf<4;++mf)
    #pragma unroll
    for(int nf=0;nf<4;++nf) acc[mf][nf] = (floatx4){0,0,0,0};
  // prologue: stage tile 0 -> buf 0
  #pragma unroll
  for(int i=0;i<4;++i){ gll16(Ag[i], Al[i]); gll16(Wg[i], Wl[i]); }
  for(int kt=0; kt<8; ++kt){
    int cur = kt&1;
    if(kt<7){
      int k0n = (kt+1)*64, off = (cur^1)*8192;
      #pragma unroll
      for(int i=0;i<4;++i){ gll16(Ag[i]+k0n, Al[i]+off); gll16(Wg[i]+k0n, Wl[i]+off); }
      asm volatile("s_waitcnt vmcnt(8)" ::: "memory");   // tile kt's 8 loads landed
    } else {
      asm volatile("s_waitcnt vmcnt(0)" ::: "memory");
    }
    __builtin_amdgcn_s_barrier();                        // all waves' tile-kt loads visible
    __builtin_amdgcn_sched_barrier(0);
    const unsigned short* Ab = &Asl[cur][0];
    const unsigned short* Wbb = &Wsl[cur][0];
    #pragma unroll
    for(int kk=0; kk<2; ++kk){
      short8 av[4], wv[4];
      #pragma unroll
      for(int mf=0;mf<4;++mf){
        int row = wr*64 + mf*16 + ln16;
        int sread = (kk*4 + quad) ^ (row&7);
        av[mf] = *(const short8*)(Ab + row*64 + sread*8);
      }
      #pragma unroll
      for(int nf=0;nf<4;++nf){
        int row = wc*64 + nf*16 + ln16;
        int sread = (kk*4 + quad) ^ (row&7);
        wv[nf] = *(const short8*)(Wbb + row*64 + sread*8);
      }
      #pragma unroll
      for(int mf=0;mf<4;++mf)
        #pragma unroll
        for(int nf=0;nf<4;++nf)
          acc[mf][nf] = MFMA_BF16(av[mf], wv[nf], acc[mf][nf], 0,0,0);
    }
    if(kt<7){
      __builtin_amdgcn_sched_barrier(0);
      __builtin_amdgcn_s_barrier();   // all waves done reading buf cur -> next iter may overwrite
    }
  }
  if(MODE==1){
    float gs[4]={0,0,0,0}, gs2[4]={0,0,0,0};
    #pragma unroll
    for(int mf=0;mf<4;++mf){
      int mb = m0 + wr*64 + mf*16 + quad*4;
      #pragma unroll
      for(int nf=0;nf<4;++nf){
        int col = n0 + wc*64 + nf*16 + ln16;
        float bv = bias[col];
        float gv = gamma[col];
        #pragma unroll
        for(int r=0;r<4;++r){
          size_t ix = (size_t)(mb+r)*512 + col;
          float val = r1[ix] + r2[ix] + gv*(acc[mf][nf][r] + bv);
          outf[ix] = val;
          gs[nf] += val; gs2[nf] += val*val;
        }
      }
    }
    float* stats = (float*)outb;
    int btq = m0 >> 10;
    #pragma unroll
    for(int nf=0;nf<4;++nf){
      float sv  = wave_sum(gs[nf]);
      float sv2 = wave_sum(gs2[nf]);
      if(l==0){
        int g = (n0 + wc*64 + nf*16) >> 4;
        atomicAdd(&stats[(btq*32+g)*2],   sv);
        atomicAdd(&stats[(btq*32+g)*2+1], sv2);
      }
    }
    return;
  }
  #pragma unroll
  for(int mf=0;mf<4;++mf){
    int mb = m0 + wr*64 + mf*16 + quad*4;
    #pragma unroll
    for(int nf=0;nf<4;++nf){
      int col = n0 + wc*64 + nf*16 + ln16;
      float bv = bias[col];
      if(MODE==0){
        #pragma unroll
        for(int r=0;r<4;++r){
          int m = mb + r;
          if(m < M) outb[(size_t)m*512 + col] = f2bf((acc[mf][nf][r] + bv)*scale);
        }
      } else if(MODE==2){
        float gv = gamma[col];
        int bt = mb >> 10;
        int hw0 = mb & 1023;
        float4 ov;
        ov.x = r1[(size_t)(mb+0)*512+col] + gv*(acc[mf][nf][0]+bv);
        ov.y = r1[(size_t)(mb+1)*512+col] + gv*(acc[mf][nf][1]+bv);
        ov.z = r1[(size_t)(mb+2)*512+col] + gv*(acc[mf][nf][2]+bv);
        ov.w = r1[(size_t)(mb+3)*512+col] + gv*(acc[mf][nf][3]+bv);
        *(float4*)(outf + (size_t)bt*524288 + (size_t)col*1024 + hw0) = ov;
      } else if(MODE==3){
        int bf = mb >> 10;
        int hw0 = mb & 1023;
        ushort4 h;
        h.x = f2bf(acc[mf][nf][0]+bv); h.y = f2bf(acc[mf][nf][1]+bv);
        h.z = f2bf(acc[mf][nf][2]+bv); h.w = f2bf(acc[mf][nf][3]+bv);
        *(ushort4*)(outb + ((size_t)bf*512 + col)*1024 + hw0) = h;
      } else if(MODE==4){
        #pragma unroll
        for(int r=0;r<4;++r){
          int m = mb + r;
          if(m < M){
            int cb = (m >= 77) ? 1 : 0;
            int key = m - 77*cb;
            outb[((size_t)cb*512 + col)*128 + key] = f2bf(acc[mf][nf][r] + bv);
          }
        }
      }
    }
  }
}

// ---------------- spatial flash attention v8: 64 q/wave, double-buffered K/V LDS staged
// via global_load_lds(16B) with counted vmcnt(4) pipeline (GEMM-v3-proven structure).
// Linear [64][64] LDS tiles; XOR swizzle slot^=(row&7) on global source AND ds_read.
// grid 1D 512: id = qt*128 + head*16 + bz, qt in 0..3 (256 q rows per block).
__global__ __launch_bounds__(256, 2) void attn_sp_kernel(const unsigned short* __restrict__ Q,
    const unsigned short* __restrict__ K, const unsigned short* __restrict__ VT,
    unsigned short* __restrict__ O){
  int id = blockIdx.x;
  int hb = id & 127, qt = id >> 7;
  int head = hb >> 4, bz = hb & 15;
  int b = bz >> 3, idx = bz & 7;
  int tid = threadIdx.x, wid = tid>>6, l = tid&63, quad = l>>4, ln16 = l&15;
  __shared__ unsigned short kt[2][64*64];   // [buf][key][dim], dim-slot XOR-swizzled
  __shared__ unsigned short vt[2][64*64];   // [buf][dim][key], key-slot XOR-swizzled
  size_t qbase = (size_t)bz*1024 + qt*256 + wid*64 + ln16;
  short8 qb[4][2];
  #pragma unroll
  for(int grp=0;grp<4;++grp){
    const unsigned short* qp = Q + (qbase + grp*16)*512 + head*64 + quad*8;
    qb[grp][0] = *(const short8*)(qp);
    qb[grp][1] = *(const short8*)(qp + 32);
  }
  floatx4 o[4][4];
  #pragma unroll
  for(int g=0;g<4;++g)
    #pragma unroll
    for(int d=0;d<4;++d) o[g][d] = (floatx4){0,0,0,0};
  float lr[4] = {0.f,0.f,0.f,0.f};
  int nch = idx ? 32 : 16;
  int f0  = idx ? (idx-1) : 0;
  // staging setup: slots s = i*256+tid (i=0,1) per matrix; r=s>>3, kg=s&7 (16B units)
  const unsigned short* Kg[2];
  const unsigned short* Vg[2];
  unsigned short* Kl[2];
  unsigned short* Vl[2];
  #pragma unroll
  for(int i=0;i<2;++i){
    int s = i*256 + tid;
    int r = s>>3, kg = s&7;
    int kgs = kg ^ (r&7);
    Kg[i] = K  + ((size_t)b*8*1024 + r)*512 + head*64 + kgs*8;       // + (f*1024+kk0)*512
    Vg[i] = VT + ((size_t)b*8*512 + head*64 + r)*1024 + kgs*8;       // + f*524288 + kk0
    Kl[i] = &kt[0][0] + s*8;
    Vl[i] = &vt[0][0] + s*8;
  }
  // prologue: stage chunk 0 -> buf 0
  {
    size_t koff = (size_t)f0*1024*512;
    size_t voff = (size_t)f0*524288;
    gll16(Kg[0]+koff, Kl[0]); gll16(Kg[1]+koff, Kl[1]);
    gll16(Vg[0]+voff, Vl[0]); gll16(Vg[1]+voff, Vl[1]);
  }
  int sw = ln16 & 7;
  for(int ch=0; ch<nch; ++ch){
    int bf_ = ch & 1;
    if(ch+1 < nch){
      int f = f0 + ((ch+1)>>4);
      int kk0 = ((ch+1)&15)*64;
      size_t koff = ((size_t)f*1024 + kk0)*512;
      size_t voff = (size_t)f*524288 + kk0;
      int lo = (bf_^1)*4096;
      gll16(Kg[0]+koff, Kl[0]+lo); gll16(Kg[1]+koff, Kl[1]+lo);
      gll16(Vg[0]+voff, Vl[0]+lo); gll16(Vg[1]+voff, Vl[1]+lo);
      asm volatile("s_waitcnt vmcnt(4)" ::: "memory");  // chunk ch's 4 loads landed
    } else {
      asm volatile("s_waitcnt vmcnt(0)" ::: "memory");
    }
    __builtin_amdgcn_s_barrier();      // all waves' chunk-ch loads visible
    __builtin_amdgcn_sched_barrier(0);
    const unsigned short* ktb = &kt[bf_][0];
    const unsigned short* vtb = &vt[bf_][0];
    #pragma unroll
    for(int g=0; g<4; ++g){
      int krow = g*16 + ln16;
      short8 k0 = *(const short8*)(ktb + krow*64 + ((quad  )^sw)*8);
      short8 k1 = *(const short8*)(ktb + krow*64 + ((quad+4)^sw)*8);
      short4v va[4];
      int sl = g*2 + (quad>>1);
      int hh = (quad&1)*4;
      #pragma unroll
      for(int dc=0; dc<4; ++dc){
        int vrow = dc*16 + ln16;
        va[dc] = *(const short4v*)(vtb + vrow*64 + ((sl^sw)*8) + hh);
      }
      #pragma unroll
      for(int grp=0; grp<4; ++grp){
        floatx4 s = {0,0,0,0};
        s = MFMA_BF16(k0, qb[grp][0], s, 0,0,0);
        s = MFMA_BF16(k1, qb[grp][1], s, 0,0,0);
        float p0 = __builtin_amdgcn_exp2f(s[0]);
        float p1 = __builtin_amdgcn_exp2f(s[1]);
        float p2 = __builtin_amdgcn_exp2f(s[2]);
        float p3 = __builtin_amdgcn_exp2f(s[3]);
        lr[grp] += (p0+p1)+(p2+p3);
        uint2 pu; pu.x = pack_bf(p0,p1); pu.y = pack_bf(p2,p3);
        short4v pb = __builtin_bit_cast(short4v, pu);
        #pragma unroll
        for(int dc=0; dc<4; ++dc)
          o[grp][dc] = MFMA16(va[dc], pb, o[grp][dc]);
      }
    }
    if(ch+1 < nch){
      __builtin_amdgcn_sched_barrier(0);
      __builtin_amdgcn_s_barrier();    // all waves done reading buf bf_ before restage
    }
  }
  #pragma unroll
  for(int grp=0; grp<4; ++grp){
    float lt = lr[grp];
    lt += __shfl_xor(lt, 16); lt += __shfl_xor(lt, 32);
    float inv = __builtin_amdgcn_rcpf(lt);
    size_t orow = qbase + grp*16;
    unsigned short* op = O + orow*512 + head*64 + quad*4;
    #pragma unroll
    for(int dc=0; dc<4; ++dc){
      uint2 pk;
      pk.x = pack_bf(o[grp][dc][0]*inv, o[grp][dc][1]*inv);
      pk.y = pack_bf(o[grp][dc][2]*inv, o[grp][dc][3]*inv);
      *(uint2*)(op + dc*16) = pk;
    }
  }
}

// ---------------- cross attention: 77 keys (2 chunks of 64, masked), 32 q/wave, dbuf
__global__ __launch_bounds__(256) void attn_ca_kernel(const unsigned short* __restrict__ Q,
    const unsigned short* __restrict__ K2, const unsigned short* __restrict__ V2T,
    unsigned short* __restrict__ O){
  int id = blockIdx.x;
  int hb = id & 127, qt = id >> 7;
  int head = hb >> 4, bt = hb & 15;
  int cb = bt & 1;
  int tid = threadIdx.x, wid = tid>>6, l = tid&63, quad = l>>4, ln16 = l&15;
  __shared__ unsigned short vt[2][64*72];
  __shared__ unsigned short kt[2][64*72];
  size_t qbase = (size_t)bt*1024 + qt*128 + wid*32 + ln16;
  short8 qb[2][2];
  #pragma unroll
  for(int grp=0;grp<2;++grp){
    const unsigned short* qp = Q + (qbase + grp*16)*512 + head*64 + quad*8;
    qb[grp][0] = *(const short8*)(qp);
    qb[grp][1] = *(const short8*)(qp + 32);
  }
  floatx4 o[2][4];
  #pragma unroll
  for(int g=0;g<2;++g)
    #pragma unroll
    for(int d=0;d<4;++d) o[g][d] = (floatx4){0,0,0,0};
  float lr[2] = {0.f,0.f};
  int sr = tid>>2, sc0 = (tid&3)*16;
  short8 pv0, pv1, pk0, pk1;
  {
    const unsigned short* vp = V2T + (((size_t)cb*512) + head*64 + sr)*128 + sc0;
    pv0 = *(const short8*)(vp); pv1 = *(const short8*)(vp + 8);
    const unsigned short* kp = K2 + ((size_t)cb*77 + sr)*512 + head*64 + sc0;
    pk0 = *(const short8*)(kp); pk1 = *(const short8*)(kp + 8);
  }
  for(int ch=0; ch<2; ++ch){
    int bf_ = ch & 1;
    int kk0 = ch*64;
    *(short8*)(&vt[bf_][0] + sr*72 + sc0)     = pv0;
    *(short8*)(&vt[bf_][0] + sr*72 + sc0 + 8) = pv1;
    *(short8*)(&kt[bf_][0] + sr*72 + sc0)     = pk0;
    *(short8*)(&kt[bf_][0] + sr*72 + sc0 + 8) = pk1;
    if(ch == 0){
      const unsigned short* vp = V2T + (((size_t)cb*512) + head*64 + sr)*128 + 64 + sc0;
      pv0 = *(const short8*)(vp); pv1 = *(const short8*)(vp + 8);
      const unsigned short* kp = K2 + ((size_t)cb*77 + 64 + sr)*512 + head*64 + sc0;
      pk0 = *(const short8*)(kp); pk1 = *(const short8*)(kp + 8);
    }
    __syncthreads();
    #pragma unroll
    for(int g=0; g<4; ++g){
      int kg = kk0 + g*16 + quad*4;
      const unsigned short* kr = &kt[bf_][0] + (g*16+ln16)*72 + quad*8;
      short8 k0 = *(const short8*)(kr);
      short8 k1 = *(const short8*)(kr + 32);
      short4v va[4];
      #pragma unroll
      for(int dc=0; dc<4; ++dc)
        va[dc] = *(const short4v*)(&vt[bf_][0] + (dc*16+ln16)*72 + g*16 + quad*4);
      #pragma unroll
      for(int grp=0; grp<2; ++grp){
        floatx4 s = {0,0,0,0};
        s = MFMA_BF16(k0, qb[grp][0], s, 0,0,0);
        s = MFMA_BF16(k1, qb[grp][1], s, 0,0,0);
        float p0 = (kg+0 < 77) ? __builtin_amdgcn_exp2f(s[0]) : 0.f;
        float p1 = (kg+1 < 77) ? __builtin_amdgcn_exp2f(s[1]) : 0.f;
        float p2 = (kg+2 < 77) ? __builtin_amdgcn_exp2f(s[2]) : 0.f;
        float p3 = (kg+3 < 77) ? __builtin_amdgcn_exp2f(s[3]) : 0.f;
        lr[grp] += (p0+p1)+(p2+p3);
        uint2 pu; pu.x = pack_bf(p0,p1); pu.y = pack_bf(p2,p3);
        short4v pb = __builtin_bit_cast(short4v, pu);
        #pragma unroll
        for(int dc=0; dc<4; ++dc)
          o[grp][dc] = MFMA16(va[dc], pb, o[grp][dc]);
      }
    }
  }
  #pragma unroll
  for(int grp=0; grp<2; ++grp){
    float lt = lr[grp];
    lt += __shfl_xor(lt, 16); lt += __shfl_xor(lt, 32);
    float inv = __builtin_amdgcn_rcpf(lt);
    size_t orow = qbase + grp*16;
    unsigned short* op = O + orow*512 + head*64 + quad*4;
    #pragma unroll
    for(int dc=0; dc<4; ++dc){
      uint2 pk;
      pk.x = pack_bf(o[grp][dc][0]*inv, o[grp][dc][1]*inv);
      pk.y = pack_bf(o[grp][dc][2]*inv, o[grp][dc][3]*inv);
      *(uint2*)(op + dc*16) = pk;
    }
  }
}

extern "C" void kernel_launch(void* const* d_in, const int* in_sizes, int n_in,
                              void* d_out, int out_size, void* d_ws, size_t ws_size,
                              hipStream_t stream) {
  const float* x        = (const float*)d_in[0];
  const float* ctx      = (const float*)d_in[1];
  const float* gn1w     = (const float*)d_in[2];
  const float* gn1b     = (const float*)d_in[3];
  const float* gn2w     = (const float*)d_in[4];
  const float* gn2b     = (const float*)d_in[5];
  const float* sa_lnv_w = (const float*)d_in[6];
  const float* sa_lnv_b = (const float*)d_in[7];
  const float* sa_lnl_w = (const float*)d_in[8];
  const float* sa_lnl_b = (const float*)d_in[9];
  const float* sa_qw    = (const float*)d_in[10];
  const float* sa_qb    = (const float*)d_in[11];
  const float* sa_kw    = (const float*)d_in[12];
  const float* sa_kb    = (const float*)d_in[13];
  const float* sa_vw    = (const float*)d_in[14];
  const float* sa_vb    = (const float*)d_in[15];
  const float* sa_ow    = (const float*)d_in[16];
  const float* sa_ob    = (const float*)d_in[17];
  const float* sa_gamma = (const float*)d_in[18];
  const float* ca_lnv_w = (const float*)d_in[19];
  const float* ca_lnv_b = (const float*)d_in[20];
  const float* ca_lnl_w = (const float*)d_in[21];
  const float* ca_lnl_b = (const float*)d_in[22];
  const float* ca_qw    = (const float*)d_in[23];
  const float* ca_qb    = (const float*)d_in[24];
  const float* ca_kw    = (const float*)d_in[25];
  const float* ca_kb    = (const float*)d_in[26];
  const float* ca_vw    = (const float*)d_in[27];
  const float* ca_vb    = (const float*)d_in[28];
  const float* ca_ow    = (const float*)d_in[29];
  const float* ca_ob    = (const float*)d_in[30];
  const float* ca_gamma = (const float*)d_in[31];

  const size_t BIGF = (size_t)16384*512*4;   // 33.55 MB
  const size_t BIGH = (size_t)16384*512*2;   // 16.78 MB
  char* w8 = (char*)d_ws;
  float*          xs   = (float*)(w8);
  float*          vn   = (float*)(w8 + BIGF);                  // later reused as vn2
  unsigned short* vnb  = (unsigned short*)(w8 + 2*BIGF);       // later vn2b
  unsigned short* lnlb = (unsigned short*)(w8 + 2*BIGF + 1*BIGH);
  unsigned short* Qb   = (unsigned short*)(w8 + 2*BIGF + 2*BIGH);  // later Q2
  unsigned short* Kb   = (unsigned short*)(w8 + 2*BIGF + 3*BIGH);
  unsigned short* VTb  = (unsigned short*)(w8 + 2*BIGF + 4*BIGH);  // V transposed [(bf)*512+c][1024]
  unsigned short* Ob   = (unsigned short*)(w8 + 2*BIGF + 5*BIGH);
  char* small = w8 + 2*BIGF + 6*BIGH;
  float*          st   = (float*)(small);                 // 4 KB raw [sum,sum2] per (bt,g)
  unsigned short* ctxb = (unsigned short*)(small + 4096); // 154*512*2
  unsigned short* Wb   = (unsigned short*)(small + 4096 + 157696); // 8 x 512x512 bf16
  // K2b / V2T alias the xs buffer (xs is dead after the sa O-projection)
  unsigned short* K2b  = (unsigned short*)(w8);                     // rows 0..153 valid; reads to 204 finite
  unsigned short* V2T  = (unsigned short*)(w8 + 1048576);           // 2*512*128 bf16
  float* xs2 = (float*)d_out;   // d_out doubles as xs2; fully overwritten by final GEMM

  const float QS = 0.125f * LOG2E;   // fold softmax log2e into Q scale (exp2 path)

  cvtw_kernel<<<dim3(256,8),256,0,stream>>>(sa_qw, sa_kw, sa_vw, sa_ow, ca_qw, ca_kw, ca_vw, ca_ow, Wb);
  gn1_kernel<<<dim3(32,16),256,0,stream>>>(x, gn1w, gn1b, xs);
  ln_dual_kernel<<<4096,256,0,stream>>>(xs, sa_lnv_w, sa_lnv_b, sa_lnl_w, sa_lnl_b, vn, vnb, lnlb);
  gemm128_kernel<0><<<dim3(128,4),256,0,stream>>>(vnb,  Wb+0*262144, sa_qb, 16384, QS,   Qb, nullptr, nullptr, nullptr, nullptr);
  gemm128_kernel<0><<<dim3(128,4),256,0,stream>>>(lnlb, Wb+1*262144, sa_kb, 16384, 1.0f, Kb, nullptr, nullptr, nullptr, nullptr);
  gemm128_kernel<3><<<dim3(128,4),256,0,stream>>>(lnlb, Wb+2*262144, sa_vb, 16384, 1.0f, VTb, nullptr, nullptr, nullptr, nullptr);
  attn_sp_kernel<<<512,256,0,stream>>>(Qb, Kb, VTb, Ob);
  (void)hipMemsetAsync(st, 0, 4096, stream);
  gemm128_kernel<1><<<dim3(128,4),256,0,stream>>>(Ob, Wb+3*262144, sa_ob, 16384, 1.0f, (unsigned short*)st, xs2, xs, vn, sa_gamma);
  gn2ln_kernel<<<4096,256,0,stream>>>(xs2, st, gn2w, gn2b, ca_lnv_w, ca_lnv_b, vn, vnb);
  ctxln_kernel<<<39,256,0,stream>>>(ctx, ca_lnl_w, ca_lnl_b, ctxb);
  gemm128_kernel<0><<<dim3(2,4),256,0,stream>>>(ctxb, Wb+5*262144, ca_kb, 154, 1.0f, K2b, nullptr, nullptr, nullptr, nullptr);
  (void)hipMemsetAsync(V2T, 0, (size_t)2*512*128*2, stream);
  gemm128_kernel<4><<<dim3(2,4),256,0,stream>>>(ctxb, Wb+6*262144, ca_vb, 154, 1.0f, V2T, nullptr, nullptr, nullptr, nullptr);
  gemm128_kernel<0><<<dim3(128,4),256,0,stream>>>(vnb, Wb+4*262144, ca_qb, 16384, QS, Qb, nullptr, nullptr, nullptr, nullptr);
  attn_ca_kernel<<<1024,256,0,stream>>>(Qb, K2b, V2T, Ob);
  gemm128_kernel<2><<<dim3(128,4),256,0,stream>>>(Ob, Wb+7*262144, ca_ob, 16384, 1.0f, nullptr, (float*)d_out, vn, nullptr, ca_gamma);
}

// Round 6
// 406.919 us; speedup vs baseline: 1.0724x; 1.0724x over previous
//
#include <hip/hip_runtime.h>

typedef __attribute__((ext_vector_type(8))) short short8;
typedef __attribute__((ext_vector_type(4))) short short4v;
typedef __attribute__((ext_vector_type(4))) float floatx4;

#define MFMA_BF16 __builtin_amdgcn_mfma_f32_16x16x32_bf16
#define LOG2E 1.44269504088896340736f

// K=16 bf16 MFMA (v_mfma_f32_16x16x16_bf16, A/B = 4 bf16 per lane).
// Guarded so the HIP host pass never parses the target builtin.
__device__ inline floatx4 MFMA16(short4v a, short4v b, floatx4 c){
#if defined(__HIP_DEVICE_COMPILE__)
  return __builtin_amdgcn_mfma_f32_16x16x16bf16_1k(a, b, c, 0, 0, 0);
#else
  return c;
#endif
}

// async global->LDS 16B (dwordx4). LDS dest must be wave-linear (base + lane*16).
__device__ inline void gll16(const unsigned short* g, unsigned short* l){
#if defined(__HIP_DEVICE_COMPILE__)
  __builtin_amdgcn_global_load_lds(
      (const __attribute__((address_space(1))) unsigned int*)g,
      (__attribute__((address_space(3))) unsigned int*)l, 16, 0, 0);
#else
  (void)g; (void)l;
#endif
}

__device__ inline unsigned short f2bf(float x){
  unsigned int u = __float_as_uint(x);
  u += 0x7fffu + ((u >> 16) & 1u);
  return (unsigned short)(u >> 16);
}
// truncating bf16 pair pack: (hi<<16)|lo, 1 instr
__device__ inline unsigned pack_bf(float lo, float hi){
  return __builtin_amdgcn_perm(__float_as_uint(hi), __float_as_uint(lo), 0x07060302u);
}

__device__ inline float wave_sum(float v){
  #pragma unroll
  for(int m=32;m>=1;m>>=1) v += __shfl_xor(v,m);
  return v;
}

// ---------------- GroupNorm1 (stats+apply+transpose). x:(BT,C,HW) -> xs:(BT,HW,C)
__global__ __launch_bounds__(256) void gn1_kernel(const float* __restrict__ x,
    const float* __restrict__ w, const float* __restrict__ b, float* __restrict__ xs){
  int g = blockIdx.x, bt = blockIdx.y, tid = threadIdx.x;
  const float* xp = x + ((size_t)bt*512 + g*16)*1024;
  float s=0.f, s2=0.f;
  #pragma unroll
  for(int it=0; it<16; ++it){
    float4 v = *(const float4*)(xp + it*1024 + tid*4);
    s  += v.x+v.y+v.z+v.w;
    s2 += v.x*v.x+v.y*v.y+v.z*v.z+v.w*v.w;
  }
  __shared__ float red[8];
  s = wave_sum(s); s2 = wave_sum(s2);
  int wid = tid>>6;
  if((tid&63)==0){ red[wid*2]=s; red[wid*2+1]=s2; }
  __syncthreads();
  s  = red[0]+red[2]+red[4]+red[6];
  s2 = red[1]+red[3]+red[5]+red[7];
  float mean = s * (1.f/16384.f);
  float var  = s2 * (1.f/16384.f) - mean*mean;
  float rinv = rsqrtf(var + 1e-5f);
  int c = tid & 15, h0 = tid >> 4;
  float sc = w[g*16+c]*rinv;
  float sh = b[g*16+c] - mean*sc;
  const float* xcol = xp + (size_t)c*1024;
  float* op = xs + (size_t)bt*1024*512 + g*16 + c;
  #pragma unroll 4
  for(int it=0; it<64; ++it){
    int hw = h0 + it*16;
    op[(size_t)hw*512] = xcol[hw]*sc + sh;
  }
}

// ---------------- Dual LayerNorm per row: vn (f32+bf16) with lnv params, lnl (bf16)
__global__ __launch_bounds__(256) void ln_dual_kernel(const float* __restrict__ xs,
    const float* __restrict__ lvw, const float* __restrict__ lvb,
    const float* __restrict__ llw, const float* __restrict__ llb,
    float* __restrict__ vn, unsigned short* __restrict__ vnb, unsigned short* __restrict__ lnlb){
  int wid = threadIdx.x>>6, l = threadIdx.x&63;
  size_t row = (size_t)blockIdx.x*4 + wid;
  const float* xp = xs + row*512;
  float4 a = *(const float4*)(xp + l*4);
  float4 c = *(const float4*)(xp + 256 + l*4);
  float s  = a.x+a.y+a.z+a.w + c.x+c.y+c.z+c.w;
  float s2 = a.x*a.x+a.y*a.y+a.z*a.z+a.w*a.w + c.x*c.x+c.y*c.y+c.z*c.z+c.w*c.w;
  s = wave_sum(s); s2 = wave_sum(s2);
  float mean = s*(1.f/512.f);
  float rinv = rsqrtf(s2*(1.f/512.f) - mean*mean + 1e-5f);
  int c0 = l*4, c1 = 256 + l*4;
  float y[8] = {(a.x-mean)*rinv,(a.y-mean)*rinv,(a.z-mean)*rinv,(a.w-mean)*rinv,
                (c.x-mean)*rinv,(c.y-mean)*rinv,(c.z-mean)*rinv,(c.w-mean)*rinv};
  float4 o0, o1;
  o0.x=y[0]*lvw[c0+0]+lvb[c0+0]; o0.y=y[1]*lvw[c0+1]+lvb[c0+1];
  o0.z=y[2]*lvw[c0+2]+lvb[c0+2]; o0.w=y[3]*lvw[c0+3]+lvb[c0+3];
  o1.x=y[4]*lvw[c1+0]+lvb[c1+0]; o1.y=y[5]*lvw[c1+1]+lvb[c1+1];
  o1.z=y[6]*lvw[c1+2]+lvb[c1+2]; o1.w=y[7]*lvw[c1+3]+lvb[c1+3];
  *(float4*)(vn + row*512 + c0) = o0;
  *(float4*)(vn + row*512 + c1) = o1;
  ushort4 h;
  h.x=f2bf(o0.x); h.y=f2bf(o0.y); h.z=f2bf(o0.z); h.w=f2bf(o0.w);
  *(ushort4*)(vnb + row*512 + c0) = h;
  h.x=f2bf(o1.x); h.y=f2bf(o1.y); h.z=f2bf(o1.z); h.w=f2bf(o1.w);
  *(ushort4*)(vnb + row*512 + c1) = h;
  h.x=f2bf(y[0]*llw[c0+0]+llb[c0+0]); h.y=f2bf(y[1]*llw[c0+1]+llb[c0+1]);
  h.z=f2bf(y[2]*llw[c0+2]+llb[c0+2]); h.w=f2bf(y[3]*llw[c0+3]+llb[c0+3]);
  *(ushort4*)(lnlb + row*512 + c0) = h;
  h.x=f2bf(y[4]*llw[c1+0]+llb[c1+0]); h.y=f2bf(y[5]*llw[c1+1]+llb[c1+1]);
  h.z=f2bf(y[6]*llw[c1+2]+llb[c1+2]); h.w=f2bf(y[7]*llw[c1+3]+llb[c1+3]);
  *(ushort4*)(lnlb + row*512 + c1) = h;
}

// ---------------- fused GN2-apply + LayerNorm (ca_lnv) -> vn2 f32 + bf16
// st holds RAW [sum, sum2] per (bt,g) accumulated by the MODE1 GEMM epilogue.
__global__ __launch_bounds__(256) void gn2ln_kernel(const float* __restrict__ xs2, const float* __restrict__ st,
    const float* __restrict__ gw, const float* __restrict__ gb,
    const float* __restrict__ lw, const float* __restrict__ lb,
    float* __restrict__ vn2, unsigned short* __restrict__ vn2b){
  int wid = threadIdx.x>>6, l = threadIdx.x&63;
  size_t row = (size_t)blockIdx.x*4 + wid;
  int bt = (int)(row >> 10);
  const float* xp = xs2 + row*512;
  float4 a = *(const float4*)(xp + l*4);
  float4 c = *(const float4*)(xp + 256 + l*4);
  int c0 = l*4, c1 = 256 + l*4;
  int g0 = c0>>4, g1 = c1>>4;
  float sm0 = st[(bt*32+g0)*2], sq0 = st[(bt*32+g0)*2+1];
  float sm1 = st[(bt*32+g1)*2], sq1 = st[(bt*32+g1)*2+1];
  float m0 = sm0*(1.f/16384.f);
  float r0 = rsqrtf(sq0*(1.f/16384.f) - m0*m0 + 1e-5f);
  float m1 = sm1*(1.f/16384.f);
  float r1 = rsqrtf(sq1*(1.f/16384.f) - m1*m1 + 1e-5f);
  float y[8];
  y[0]=(a.x-m0)*r0*gw[c0+0]+gb[c0+0]; y[1]=(a.y-m0)*r0*gw[c0+1]+gb[c0+1];
  y[2]=(a.z-m0)*r0*gw[c0+2]+gb[c0+2]; y[3]=(a.w-m0)*r0*gw[c0+3]+gb[c0+3];
  y[4]=(c.x-m1)*r1*gw[c1+0]+gb[c1+0]; y[5]=(c.y-m1)*r1*gw[c1+1]+gb[c1+1];
  y[6]=(c.z-m1)*r1*gw[c1+2]+gb[c1+2]; y[7]=(c.w-m1)*r1*gw[c1+3]+gb[c1+3];
  float s=0.f, s2=0.f;
  #pragma unroll
  for(int i=0;i<8;++i){ s += y[i]; s2 += y[i]*y[i]; }
  s = wave_sum(s); s2 = wave_sum(s2);
  float mean = s*(1.f/512.f);
  float rinv = rsqrtf(s2*(1.f/512.f) - mean*mean + 1e-5f);
  float4 o0, o1;
  o0.x=(y[0]-mean)*rinv*lw[c0+0]+lb[c0+0]; o0.y=(y[1]-mean)*rinv*lw[c0+1]+lb[c0+1];
  o0.z=(y[2]-mean)*rinv*lw[c0+2]+lb[c0+2]; o0.w=(y[3]-mean)*rinv*lw[c0+3]+lb[c0+3];
  o1.x=(y[4]-mean)*rinv*lw[c1+0]+lb[c1+0]; o1.y=(y[5]-mean)*rinv*lw[c1+1]+lb[c1+1];
  o1.z=(y[6]-mean)*rinv*lw[c1+2]+lb[c1+2]; o1.w=(y[7]-mean)*rinv*lw[c1+3]+lb[c1+3];
  *(float4*)(vn2 + row*512 + c0) = o0;
  *(float4*)(vn2 + row*512 + c1) = o1;
  ushort4 h;
  h.x=f2bf(o0.x); h.y=f2bf(o0.y); h.z=f2bf(o0.z); h.w=f2bf(o0.w);
  *(ushort4*)(vn2b + row*512 + c0) = h;
  h.x=f2bf(o1.x); h.y=f2bf(o1.y); h.z=f2bf(o1.z); h.w=f2bf(o1.w);
  *(ushort4*)(vn2b + row*512 + c1) = h;
}

// ---------------- context LayerNorm (ca_lnl) -> bf16, 154 rows
__global__ __launch_bounds__(256) void ctxln_kernel(const float* __restrict__ ctx,
    const float* __restrict__ lw, const float* __restrict__ lb, unsigned short* __restrict__ out){
  int wid = threadIdx.x>>6, l = threadIdx.x&63;
  int row = blockIdx.x*4 + wid;
  if(row >= 154) return;
  const float* xp = ctx + (size_t)row*512;
  float4 a = *(const float4*)(xp + l*4);
  float4 c = *(const float4*)(xp + 256 + l*4);
  float s  = a.x+a.y+a.z+a.w + c.x+c.y+c.z+c.w;
  float s2 = a.x*a.x+a.y*a.y+a.z*a.z+a.w*a.w + c.x*c.x+c.y*c.y+c.z*c.z+c.w*c.w;
  s = wave_sum(s); s2 = wave_sum(s2);
  float mean = s*(1.f/512.f);
  float rinv = rsqrtf(s2*(1.f/512.f) - mean*mean + 1e-5f);
  int c0 = l*4, c1 = 256 + l*4;
  ushort4 h;
  h.x=f2bf((a.x-mean)*rinv*lw[c0+0]+lb[c0+0]); h.y=f2bf((a.y-mean)*rinv*lw[c0+1]+lb[c0+1]);
  h.z=f2bf((a.z-mean)*rinv*lw[c0+2]+lb[c0+2]); h.w=f2bf((a.w-mean)*rinv*lw[c0+3]+lb[c0+3]);
  *(ushort4*)(out + (size_t)row*512 + c0) = h;
  h.x=f2bf((c.x-mean)*rinv*lw[c1+0]+lb[c1+0]); h.y=f2bf((c.y-mean)*rinv*lw[c1+1]+lb[c1+1]);
  h.z=f2bf((c.z-mean)*rinv*lw[c1+2]+lb[c1+2]); h.w=f2bf((c.w-mean)*rinv*lw[c1+3]+lb[c1+3]);
  *(ushort4*)(out + (size_t)row*512 + c1) = h;
}

// ---------------- weight fp32 -> bf16 (8 weights of 512x512)
__global__ __launch_bounds__(256) void cvtw_kernel(const float* s0, const float* s1, const float* s2,
    const float* s3, const float* s4, const float* s5, const float* s6, const float* s7,
    unsigned short* __restrict__ dst){
  const float* srcs[8] = {s0,s1,s2,s3,s4,s5,s6,s7};
  int w = blockIdx.y;
  const float* src = srcs[w];
  int i = (blockIdx.x*256 + threadIdx.x)*4;
  float4 v = *(const float4*)(src + i);
  ushort4 h; h.x=f2bf(v.x); h.y=f2bf(v.y); h.z=f2bf(v.z); h.w=f2bf(v.w);
  *(ushort4*)(dst + (size_t)w*262144 + i) = h;
}

// ======== shared GEMM core: 128x128 tile, BK=64, dbuf LDS, counted vmcnt pipeline ========
// Computes acc[4][4] for block tile (m0,n0) of out = A[M,512] @ W[512,512]^T.
// Asl/Wsl are [2][128*64] LDS buffers. Returns with acc filled.
__device__ inline void gemm_core(const unsigned short* __restrict__ A,
    const unsigned short* __restrict__ W, int M, int m0, int n0,
    unsigned short* Asl, unsigned short* Wsl, floatx4 acc[4][4]){
  int tid = threadIdx.x, l = tid&63, quad = l>>4, ln16 = l&15;
  int wid = tid>>6;
  int wr = wid>>1, wc = wid&1;
  const unsigned short* Ag[4];
  const unsigned short* Wg[4];
  unsigned short* Al[4];
  unsigned short* Wl[4];
  #pragma unroll
  for(int i=0;i<4;++i){
    int s = i*256 + tid;
    int row = s>>3, kg = s&7;
    int kgs = kg ^ (row&7);
    int ar = m0+row; if(ar > M-1) ar = M-1;
    Ag[i] = A + (size_t)ar*512 + kgs*8;
    Wg[i] = W + (size_t)(n0+row)*512 + kgs*8;
    Al[i] = Asl + row*64 + kg*8;
    Wl[i] = Wsl + row*64 + kg*8;
  }
  #pragma unroll
  for(int mf=0;mf<4;++mf)
    #pragma unroll
    for(int nf=0;nf<4;++nf) acc[mf][nf] = (floatx4){0,0,0,0};
  // prologue: stage tile 0 -> buf 0
  #pragma unroll
  for(int i=0;i<4;++i){ gll16(Ag[i], Al[i]); gll16(Wg[i], Wl[i]); }
  for(int kt=0; kt<8; ++kt){
    int cur = kt&1;
    if(kt<7){
      int k0n = (kt+1)*64, off = (cur^1)*8192;
      #pragma unroll
      for(int i=0;i<4;++i){ gll16(Ag[i]+k0n, Al[i]+off); gll16(Wg[i]+k0n, Wl[i]+off); }
      asm volatile("s_waitcnt vmcnt(8)" ::: "memory");   // tile kt's 8 loads landed
    } else {
      asm volatile("s_waitcnt vmcnt(0)" ::: "memory");
    }
    __builtin_amdgcn_s_barrier();                        // all waves' tile-kt loads visible
    __builtin_amdgcn_sched_barrier(0);
    const unsigned short* Ab = Asl + cur*8192;
    const unsigned short* Wbb = Wsl + cur*8192;
    #pragma unroll
    for(int kk=0; kk<2; ++kk){
      short8 av[4], wv[4];
      #pragma unroll
      for(int mf=0;mf<4;++mf){
        int row = wr*64 + mf*16 + ln16;
        int sread = (kk*4 + quad) ^ (row&7);
        av[mf] = *(const short8*)(Ab + row*64 + sread*8);
      }
      #pragma unroll
      for(int nf=0;nf<4;++nf){
        int row = wc*64 + nf*16 + ln16;
        int sread = (kk*4 + quad) ^ (row&7);
        wv[nf] = *(const short8*)(Wbb + row*64 + sread*8);
      }
      #pragma unroll
      for(int mf=0;mf<4;++mf)
        #pragma unroll
        for(int nf=0;nf<4;++nf)
          acc[mf][nf] = MFMA_BF16(av[mf], wv[nf], acc[mf][nf], 0,0,0);
    }
    if(kt<7){
      __builtin_amdgcn_sched_barrier(0);
      __builtin_amdgcn_s_barrier();   // all waves done reading buf cur -> next iter may overwrite
    }
  }
}

// ---------------- standalone GEMM with epilogue modes (MODE 1 and 2 used)
// MODE 0: outb = bf16((acc+bias)*scale)                       [natural]
// MODE 1: outf = r1 + r2 + gamma*(acc+bias); group sums -> (float*)outb via atomics
// MODE 2: outf[bt,c,hw] = r1 + gamma*(acc+bias)               [transposed f32]
template<int MODE>
__global__ __launch_bounds__(256) void gemm128_kernel(const unsigned short* __restrict__ A,
    const unsigned short* __restrict__ W, const float* __restrict__ bias, int M, float scale,
    unsigned short* __restrict__ outb, float* __restrict__ outf,
    const float* __restrict__ r1, const float* __restrict__ r2, const float* __restrict__ gamma){
  __shared__ unsigned short Asl[2][128*64];
  __shared__ unsigned short Wsl[2][128*64];
  int tid = threadIdx.x, l = tid&63, wid = tid>>6, quad = l>>4, ln16 = l&15;
  int wr = wid>>1, wc = wid&1;
  int m0 = blockIdx.x*128, n0 = blockIdx.y*128;
  floatx4 acc[4][4];
  gemm_core(A, W, M, m0, n0, &Asl[0][0], &Wsl[0][0], acc);
  if(MODE==1){
    float gs[4]={0,0,0,0}, gs2[4]={0,0,0,0};
    #pragma unroll
    for(int mf=0;mf<4;++mf){
      int mb = m0 + wr*64 + mf*16 + quad*4;
      #pragma unroll
      for(int nf=0;nf<4;++nf){
        int col = n0 + wc*64 + nf*16 + ln16;
        float bv = bias[col];
        float gv = gamma[col];
        #pragma unroll
        for(int r=0;r<4;++r){
          size_t ix = (size_t)(mb+r)*512 + col;
          float val = r1[ix] + r2[ix] + gv*(acc[mf][nf][r] + bv);
          outf[ix] = val;
          gs[nf] += val; gs2[nf] += val*val;
        }
      }
    }
    float* stats = (float*)outb;
    int btq = m0 >> 10;
    #pragma unroll
    for(int nf=0;nf<4;++nf){
      float sv  = wave_sum(gs[nf]);
      float sv2 = wave_sum(gs2[nf]);
      if(l==0){
        int g = (n0 + wc*64 + nf*16) >> 4;
        atomicAdd(&stats[(btq*32+g)*2],   sv);
        atomicAdd(&stats[(btq*32+g)*2+1], sv2);
      }
    }
    return;
  }
  #pragma unroll
  for(int mf=0;mf<4;++mf){
    int mb = m0 + wr*64 + mf*16 + quad*4;
    #pragma unroll
    for(int nf=0;nf<4;++nf){
      int col = n0 + wc*64 + nf*16 + ln16;
      float bv = bias[col];
      if(MODE==0){
        #pragma unroll
        for(int r=0;r<4;++r){
          int m = mb + r;
          if(m < M) outb[(size_t)m*512 + col] = f2bf((acc[mf][nf][r] + bv)*scale);
        }
      } else if(MODE==2){
        float gv = gamma[col];
        int bt = mb >> 10;
        int hw0 = mb & 1023;
        float4 ov;
        ov.x = r1[(size_t)(mb+0)*512+col] + gv*(acc[mf][nf][0]+bv);
        ov.y = r1[(size_t)(mb+1)*512+col] + gv*(acc[mf][nf][1]+bv);
        ov.z = r1[(size_t)(mb+2)*512+col] + gv*(acc[mf][nf][2]+bv);
        ov.w = r1[(size_t)(mb+3)*512+col] + gv*(acc[mf][nf][3]+bv);
        *(float4*)(outf + (size_t)bt*524288 + (size_t)col*1024 + hw0) = ov;
      }
    }
  }
}

// ---------------- fused sa Q/K/V projections in ONE launch. grid (128,4,3), z selects:
// z=0: Qb = bf16((vnb@Wq^T + qb)*qs)   z=1: Kb = bf16(lnlb@Wk^T + kb)
// z=2: VTb[(m>>10)*512+col][m&1023] = bf16(lnlb@Wv^T + vb)
__global__ __launch_bounds__(256) void gemm_qkv_kernel(
    const unsigned short* __restrict__ Aq, const unsigned short* __restrict__ Akv,
    const unsigned short* __restrict__ Wbase,
    const float* __restrict__ bq, const float* __restrict__ bk, const float* __restrict__ bv,
    float qs,
    unsigned short* __restrict__ outQ, unsigned short* __restrict__ outK, unsigned short* __restrict__ outVT){
  __shared__ unsigned short Asl[2][128*64];
  __shared__ unsigned short Wsl[2][128*64];
  int tid = threadIdx.x, l = tid&63, wid = tid>>6, quad = l>>4, ln16 = l&15;
  int wr = wid>>1, wc = wid&1;
  int z = blockIdx.z;
  int m0 = blockIdx.x*128, n0 = blockIdx.y*128;
  const unsigned short* A = (z==0) ? Aq : Akv;
  const unsigned short* W = Wbase + (size_t)z*262144;
  const float* bias = (z==0) ? bq : ((z==1) ? bk : bv);
  floatx4 acc[4][4];
  gemm_core(A, W, 16384, m0, n0, &Asl[0][0], &Wsl[0][0], acc);
  #pragma unroll
  for(int mf=0;mf<4;++mf){
    int mb = m0 + wr*64 + mf*16 + quad*4;
    #pragma unroll
    for(int nf=0;nf<4;++nf){
      int col = n0 + wc*64 + nf*16 + ln16;
      float bv_ = bias[col];
      if(z==0){
        #pragma unroll
        for(int r=0;r<4;++r)
          outQ[(size_t)(mb+r)*512 + col] = f2bf((acc[mf][nf][r] + bv_)*qs);
      } else if(z==1){
        #pragma unroll
        for(int r=0;r<4;++r)
          outK[(size_t)(mb+r)*512 + col] = f2bf(acc[mf][nf][r] + bv_);
      } else {
        int bf = mb >> 10;
        int hw0 = mb & 1023;
        ushort4 h;
        h.x = f2bf(acc[mf][nf][0]+bv_); h.y = f2bf(acc[mf][nf][1]+bv_);
        h.z = f2bf(acc[mf][nf][2]+bv_); h.w = f2bf(acc[mf][nf][3]+bv_);
        *(ushort4*)(outVT + ((size_t)bf*512 + col)*1024 + hw0) = h;
      }
    }
  }
}

// ---------------- fused ca K2/V2T projections in ONE launch. grid (2,4,2), z selects:
// z=0: K2b = bf16(ctxb@Wck^T + ckb)  [M=154, natural]
// z=1: V2T[(cb*512+col)*128 + key] = bf16(ctxb@Wcv^T + cvb), cb=m>=77, key=m-77cb
__global__ __launch_bounds__(256) void gemm_cakv_kernel(
    const unsigned short* __restrict__ A, const unsigned short* __restrict__ Wbase,
    const float* __restrict__ bk, const float* __restrict__ bv,
    unsigned short* __restrict__ outK2, unsigned short* __restrict__ outV2T){
  __shared__ unsigned short Asl[2][128*64];
  __shared__ unsigned short Wsl[2][128*64];
  int tid = threadIdx.x, l = tid&63, wid = tid>>6, quad = l>>4, ln16 = l&15;
  int wr = wid>>1, wc = wid&1;
  int z = blockIdx.z;
  int m0 = blockIdx.x*128, n0 = blockIdx.y*128;
  const unsigned short* W = Wbase + (size_t)z*262144;
  const float* bias = (z==0) ? bk : bv;
  floatx4 acc[4][4];
  gemm_core(A, W, 154, m0, n0, &Asl[0][0], &Wsl[0][0], acc);
  #pragma unroll
  for(int mf=0;mf<4;++mf){
    int mb = m0 + wr*64 + mf*16 + quad*4;
    #pragma unroll
    for(int nf=0;nf<4;++nf){
      int col = n0 + wc*64 + nf*16 + ln16;
      float bv_ = bias[col];
      #pragma unroll
      for(int r=0;r<4;++r){
        int m = mb + r;
        if(m < 154){
          if(z==0){
            outK2[(size_t)m*512 + col] = f2bf(acc[mf][nf][r] + bv_);
          } else {
            int cb = (m >= 77) ? 1 : 0;
            int key = m - 77*cb;
            outV2T[((size_t)cb*512 + col)*128 + key] = f2bf(acc[mf][nf][r] + bv_);
          }
        }
      }
    }
  }
}

// ---------------- spatial flash attention v7 (proven best): 64 q/wave, double-buffered
// K/V LDS via register staging, 1 barrier/chunk, prefetch issued before barrier.
// grid 1D 512: id = qt*128 + head*16 + bz, qt in 0..3 (256 q rows per block).
__global__ __launch_bounds__(256, 2) void attn_sp_kernel(const unsigned short* __restrict__ Q,
    const unsigned short* __restrict__ K, const unsigned short* __restrict__ VT,
    unsigned short* __restrict__ O){
  int id = blockIdx.x;
  int hb = id & 127, qt = id >> 7;
  int head = hb >> 4, bz = hb & 15;
  int b = bz >> 3, idx = bz & 7;
  int tid = threadIdx.x, wid = tid>>6, l = tid&63, quad = l>>4, ln16 = l&15;
  __shared__ unsigned short vt[2][64*72];     // [buf][dim][key]
  __shared__ unsigned short kt[2][64*72];     // [buf][key][dim]
  size_t qbase = (size_t)bz*1024 + qt*256 + wid*64 + ln16;
  short8 qb[4][2];
  #pragma unroll
  for(int grp=0;grp<4;++grp){
    const unsigned short* qp = Q + (qbase + grp*16)*512 + head*64 + quad*8;
    qb[grp][0] = *(const short8*)(qp);
    qb[grp][1] = *(const short8*)(qp + 32);
  }
  floatx4 o[4][4];
  #pragma unroll
  for(int g=0;g<4;++g)
    #pragma unroll
    for(int d=0;d<4;++d) o[g][d] = (floatx4){0,0,0,0};
  float lr[4] = {0.f,0.f,0.f,0.f};
  int nch = idx ? 32 : 16;
  int f0  = idx ? (idx-1) : 0;
  int sr = tid>>2, sc0 = (tid&3)*16;
  short8 pv0, pv1, pk0, pk1;
  {
    const unsigned short* vp = VT + (((size_t)(b*8+f0)*512) + head*64 + sr)*1024 + sc0;
    pv0 = *(const short8*)(vp); pv1 = *(const short8*)(vp + 8);
    const unsigned short* kp = K + (((size_t)(b*8+f0))*1024 + sr)*512 + head*64 + sc0;
    pk0 = *(const short8*)(kp); pk1 = *(const short8*)(kp + 8);
  }
  for(int ch=0; ch<nch; ++ch){
    int bf_ = ch & 1;
    *(short8*)(&vt[bf_][0] + sr*72 + sc0)     = pv0;
    *(short8*)(&vt[bf_][0] + sr*72 + sc0 + 8) = pv1;
    *(short8*)(&kt[bf_][0] + sr*72 + sc0)     = pk0;
    *(short8*)(&kt[bf_][0] + sr*72 + sc0 + 8) = pk1;
    if(ch+1 < nch){
      int f = f0 + ((ch+1)>>4);
      int kk0 = ((ch+1)&15)*64;
      const unsigned short* vp = VT + (((size_t)(b*8+f)*512) + head*64 + sr)*1024 + kk0 + sc0;
      pv0 = *(const short8*)(vp); pv1 = *(const short8*)(vp + 8);
      const unsigned short* kp = K + (((size_t)(b*8+f))*1024 + kk0 + sr)*512 + head*64 + sc0;
      pk0 = *(const short8*)(kp); pk1 = *(const short8*)(kp + 8);
    }
    __syncthreads();
    #pragma unroll
    for(int g=0; g<4; ++g){
      const unsigned short* kr = &kt[bf_][0] + (g*16+ln16)*72 + quad*8;
      short8 k0 = *(const short8*)(kr);
      short8 k1 = *(const short8*)(kr + 32);
      short4v va[4];
      #pragma unroll
      for(int dc=0; dc<4; ++dc)
        va[dc] = *(const short4v*)(&vt[bf_][0] + (dc*16+ln16)*72 + g*16 + quad*4);
      #pragma unroll
      for(int grp=0; grp<4; ++grp){
        floatx4 s = {0,0,0,0};
        s = MFMA_BF16(k0, qb[grp][0], s, 0,0,0);
        s = MFMA_BF16(k1, qb[grp][1], s, 0,0,0);
        float p0 = __builtin_amdgcn_exp2f(s[0]);
        float p1 = __builtin_amdgcn_exp2f(s[1]);
        float p2 = __builtin_amdgcn_exp2f(s[2]);
        float p3 = __builtin_amdgcn_exp2f(s[3]);
        lr[grp] += (p0+p1)+(p2+p3);
        uint2 pu; pu.x = pack_bf(p0,p1); pu.y = pack_bf(p2,p3);
        short4v pb = __builtin_bit_cast(short4v, pu);
        #pragma unroll
        for(int dc=0; dc<4; ++dc)
          o[grp][dc] = MFMA16(va[dc], pb, o[grp][dc]);
      }
    }
  }
  #pragma unroll
  for(int grp=0; grp<4; ++grp){
    float lt = lr[grp];
    lt += __shfl_xor(lt, 16); lt += __shfl_xor(lt, 32);
    float inv = __builtin_amdgcn_rcpf(lt);
    size_t orow = qbase + grp*16;
    unsigned short* op = O + orow*512 + head*64 + quad*4;
    #pragma unroll
    for(int dc=0; dc<4; ++dc){
      uint2 pk;
      pk.x = pack_bf(o[grp][dc][0]*inv, o[grp][dc][1]*inv);
      pk.y = pack_bf(o[grp][dc][2]*inv, o[grp][dc][3]*inv);
      *(uint2*)(op + dc*16) = pk;
    }
  }
}

// ---------------- cross attention: 77 keys (2 chunks of 64, masked), 32 q/wave, dbuf
__global__ __launch_bounds__(256) void attn_ca_kernel(const unsigned short* __restrict__ Q,
    const unsigned short* __restrict__ K2, const unsigned short* __restrict__ V2T,
    unsigned short* __restrict__ O){
  int id = blockIdx.x;
  int hb = id & 127, qt = id >> 7;
  int head = hb >> 4, bt = hb & 15;
  int cb = bt & 1;
  int tid = threadIdx.x, wid = tid>>6, l = tid&63, quad = l>>4, ln16 = l&15;
  __shared__ unsigned short vt[2][64*72];
  __shared__ unsigned short kt[2][64*72];
  size_t qbase = (size_t)bt*1024 + qt*128 + wid*32 + ln16;
  short8 qb[2][2];
  #pragma unroll
  for(int grp=0;grp<2;++grp){
    const unsigned short* qp = Q + (qbase + grp*16)*512 + head*64 + quad*8;
    qb[grp][0] = *(const short8*)(qp);
    qb[grp][1] = *(const short8*)(qp + 32);
  }
  floatx4 o[2][4];
  #pragma unroll
  for(int g=0;g<2;++g)
    #pragma unroll
    for(int d=0;d<4;++d) o[g][d] = (floatx4){0,0,0,0};
  float lr[2] = {0.f,0.f};
  int sr = tid>>2, sc0 = (tid&3)*16;
  short8 pv0, pv1, pk0, pk1;
  {
    const unsigned short* vp = V2T + (((size_t)cb*512) + head*64 + sr)*128 + sc0;
    pv0 = *(const short8*)(vp); pv1 = *(const short8*)(vp + 8);
    const unsigned short* kp = K2 + ((size_t)cb*77 + sr)*512 + head*64 + sc0;
    pk0 = *(const short8*)(kp); pk1 = *(const short8*)(kp + 8);
  }
  for(int ch=0; ch<2; ++ch){
    int bf_ = ch & 1;
    int kk0 = ch*64;
    *(short8*)(&vt[bf_][0] + sr*72 + sc0)     = pv0;
    *(short8*)(&vt[bf_][0] + sr*72 + sc0 + 8) = pv1;
    *(short8*)(&kt[bf_][0] + sr*72 + sc0)     = pk0;
    *(short8*)(&kt[bf_][0] + sr*72 + sc0 + 8) = pk1;
    if(ch == 0){
      const unsigned short* vp = V2T + (((size_t)cb*512) + head*64 + sr)*128 + 64 + sc0;
      pv0 = *(const short8*)(vp); pv1 = *(const short8*)(vp + 8);
      const unsigned short* kp = K2 + ((size_t)cb*77 + 64 + sr)*512 + head*64 + sc0;
      pk0 = *(const short8*)(kp); pk1 = *(const short8*)(kp + 8);
    }
    __syncthreads();
    #pragma unroll
    for(int g=0; g<4; ++g){
      int kg = kk0 + g*16 + quad*4;
      const unsigned short* kr = &kt[bf_][0] + (g*16+ln16)*72 + quad*8;
      short8 k0 = *(const short8*)(kr);
      short8 k1 = *(const short8*)(kr + 32);
      short4v va[4];
      #pragma unroll
      for(int dc=0; dc<4; ++dc)
        va[dc] = *(const short4v*)(&vt[bf_][0] + (dc*16+ln16)*72 + g*16 + quad*4);
      #pragma unroll
      for(int grp=0; grp<2; ++grp){
        floatx4 s = {0,0,0,0};
        s = MFMA_BF16(k0, qb[grp][0], s, 0,0,0);
        s = MFMA_BF16(k1, qb[grp][1], s, 0,0,0);
        float p0 = (kg+0 < 77) ? __builtin_amdgcn_exp2f(s[0]) : 0.f;
        float p1 = (kg+1 < 77) ? __builtin_amdgcn_exp2f(s[1]) : 0.f;
        float p2 = (kg+2 < 77) ? __builtin_amdgcn_exp2f(s[2]) : 0.f;
        float p3 = (kg+3 < 77) ? __builtin_amdgcn_exp2f(s[3]) : 0.f;
        lr[grp] += (p0+p1)+(p2+p3);
        uint2 pu; pu.x = pack_bf(p0,p1); pu.y = pack_bf(p2,p3);
        short4v pb = __builtin_bit_cast(short4v, pu);
        #pragma unroll
        for(int dc=0; dc<4; ++dc)
          o[grp][dc] = MFMA16(va[dc], pb, o[grp][dc]);
      }
    }
  }
  #pragma unroll
  for(int grp=0; grp<2; ++grp){
    float lt = lr[grp];
    lt += __shfl_xor(lt, 16); lt += __shfl_xor(lt, 32);
    float inv = __builtin_amdgcn_rcpf(lt);
    size_t orow = qbase + grp*16;
    unsigned short* op = O + orow*512 + head*64 + quad*4;
    #pragma unroll
    for(int dc=0; dc<4; ++dc){
      uint2 pk;
      pk.x = pack_bf(o[grp][dc][0]*inv, o[grp][dc][1]*inv);
      pk.y = pack_bf(o[grp][dc][2]*inv, o[grp][dc][3]*inv);
      *(uint2*)(op + dc*16) = pk;
    }
  }
}

extern "C" void kernel_launch(void* const* d_in, const int* in_sizes, int n_in,
                              void* d_out, int out_size, void* d_ws, size_t ws_size,
                              hipStream_t stream) {
  const float* x        = (const float*)d_in[0];
  const float* ctx      = (const float*)d_in[1];
  const float* gn1w     = (const float*)d_in[2];
  const float* gn1b     = (const float*)d_in[3];
  const float* gn2w     = (const float*)d_in[4];
  const float* gn2b     = (const float*)d_in[5];
  const float* sa_lnv_w = (const float*)d_in[6];
  const float* sa_lnv_b = (const float*)d_in[7];
  const float* sa_lnl_w = (const float*)d_in[8];
  const float* sa_lnl_b = (const float*)d_in[9];
  const float* sa_qw    = (const float*)d_in[10];
  const float* sa_qb    = (const float*)d_in[11];
  const float* sa_kw    = (const float*)d_in[12];
  const float* sa_kb    = (const float*)d_in[13];
  const float* sa_vw    = (const float*)d_in[14];
  const float* sa_vb    = (const float*)d_in[15];
  const float* sa_ow    = (const float*)d_in[16];
  const float* sa_ob    = (const float*)d_in[17];
  const float* sa_gamma = (const float*)d_in[18];
  const float* ca_lnv_w = (const float*)d_in[19];
  const float* ca_lnv_b = (const float*)d_in[20];
  const float* ca_lnl_w = (const float*)d_in[21];
  const float* ca_lnl_b = (const float*)d_in[22];
  const float* ca_qw    = (const float*)d_in[23];
  const float* ca_qb    = (const float*)d_in[24];
  const float* ca_kw    = (const float*)d_in[25];
  const float* ca_kb    = (const float*)d_in[26];
  const float* ca_vw    = (const float*)d_in[27];
  const float* ca_vb    = (const float*)d_in[28];
  const float* ca_ow    = (const float*)d_in[29];
  const float* ca_ob    = (const float*)d_in[30];
  const float* ca_gamma = (const float*)d_in[31];

  const size_t BIGF = (size_t)16384*512*4;   // 33.55 MB
  const size_t BIGH = (size_t)16384*512*2;   // 16.78 MB
  char* w8 = (char*)d_ws;
  float*          xs   = (float*)(w8);
  float*          vn   = (float*)(w8 + BIGF);                  // later reused as vn2
  unsigned short* vnb  = (unsigned short*)(w8 + 2*BIGF);       // later vn2b
  unsigned short* lnlb = (unsigned short*)(w8 + 2*BIGF + 1*BIGH);
  unsigned short* Qb   = (unsigned short*)(w8 + 2*BIGF + 2*BIGH);  // later Q2
  unsigned short* Kb   = (unsigned short*)(w8 + 2*BIGF + 3*BIGH);
  unsigned short* VTb  = (unsigned short*)(w8 + 2*BIGF + 4*BIGH);  // V transposed [(bf)*512+c][1024]
  unsigned short* Ob   = (unsigned short*)(w8 + 2*BIGF + 5*BIGH);
  char* small = w8 + 2*BIGF + 6*BIGH;
  float*          st   = (float*)(small);                 // 4 KB raw [sum,sum2] per (bt,g)
  unsigned short* ctxb = (unsigned short*)(small + 4096); // 154*512*2
  unsigned short* Wb   = (unsigned short*)(small + 4096 + 157696); // 8 x 512x512 bf16
  // K2b / V2T alias the xs buffer (xs is dead after the sa O-projection)
  unsigned short* K2b  = (unsigned short*)(w8);                     // rows 0..153 valid; reads to 204 finite
  unsigned short* V2T  = (unsigned short*)(w8 + 1048576);           // 2*512*128 bf16
  float* xs2 = (float*)d_out;   // d_out doubles as xs2; fully overwritten by final GEMM

  const float QS = 0.125f * LOG2E;   // fold softmax log2e into Q scale (exp2 path)

  (void)hipMemsetAsync(st, 0, 4096, stream);   // early: st untouched until MODE1 GEMM
  cvtw_kernel<<<dim3(256,8),256,0,stream>>>(sa_qw, sa_kw, sa_vw, sa_ow, ca_qw, ca_kw, ca_vw, ca_ow, Wb);
  gn1_kernel<<<dim3(32,16),256,0,stream>>>(x, gn1w, gn1b, xs);
  ln_dual_kernel<<<4096,256,0,stream>>>(xs, sa_lnv_w, sa_lnv_b, sa_lnl_w, sa_lnl_b, vn, vnb, lnlb);
  gemm_qkv_kernel<<<dim3(128,4,3),256,0,stream>>>(vnb, lnlb, Wb, sa_qb, sa_kb, sa_vb, QS, Qb, Kb, VTb);
  attn_sp_kernel<<<512,256,0,stream>>>(Qb, Kb, VTb, Ob);
  gemm128_kernel<1><<<dim3(128,4),256,0,stream>>>(Ob, Wb+3*262144, sa_ob, 16384, 1.0f, (unsigned short*)st, xs2, xs, vn, sa_gamma);
  (void)hipMemsetAsync(V2T, 0, (size_t)2*512*128*2, stream);   // xs dead now
  gn2ln_kernel<<<4096,256,0,stream>>>(xs2, st, gn2w, gn2b, ca_lnv_w, ca_lnv_b, vn, vnb);
  ctxln_kernel<<<39,256,0,stream>>>(ctx, ca_lnl_w, ca_lnl_b, ctxb);
  gemm_cakv_kernel<<<dim3(2,4,2),256,0,stream>>>(ctxb, Wb+5*262144, ca_kb, ca_vb, K2b, V2T);
  gemm128_kernel<0><<<dim3(128,4),256,0,stream>>>(vnb, Wb+4*262144, ca_qb, 16384, QS, Qb, nullptr, nullptr, nullptr, nullptr);
  attn_ca_kernel<<<1024,256,0,stream>>>(Qb, K2b, V2T, Ob);
  gemm128_kernel<2><<<dim3(128,4),256,0,stream>>>(Ob, Wb+7*262144, ca_ob, 16384, 1.0f, nullptr, (float*)d_out, vn, nullptr, ca_gamma);
}

// Round 7
// 401.633 us; speedup vs baseline: 1.0865x; 1.0132x over previous
//
#include <hip/hip_runtime.h>

typedef __attribute__((ext_vector_type(8))) short short8;
typedef __attribute__((ext_vector_type(4))) short short4v;
typedef __attribute__((ext_vector_type(4))) float floatx4;

#define MFMA_BF16 __builtin_amdgcn_mfma_f32_16x16x32_bf16
#define LOG2E 1.44269504088896340736f

// K=16 bf16 MFMA (v_mfma_f32_16x16x16_bf16, A/B = 4 bf16 per lane).
// Guarded so the HIP host pass never parses the target builtin.
__device__ inline floatx4 MFMA16(short4v a, short4v b, floatx4 c){
#if defined(__HIP_DEVICE_COMPILE__)
  return __builtin_amdgcn_mfma_f32_16x16x16bf16_1k(a, b, c, 0, 0, 0);
#else
  return c;
#endif
}

// async global->LDS 16B (dwordx4). LDS dest must be wave-linear (base + lane*16).
__device__ inline void gll16(const unsigned short* g, unsigned short* l){
#if defined(__HIP_DEVICE_COMPILE__)
  __builtin_amdgcn_global_load_lds(
      (const __attribute__((address_space(1))) unsigned int*)g,
      (__attribute__((address_space(3))) unsigned int*)l, 16, 0, 0);
#else
  (void)g; (void)l;
#endif
}

__device__ inline unsigned short f2bf(float x){
  unsigned int u = __float_as_uint(x);
  u += 0x7fffu + ((u >> 16) & 1u);
  return (unsigned short)(u >> 16);
}
// truncating bf16 pair pack: (hi<<16)|lo, 1 instr
__device__ inline unsigned pack_bf(float lo, float hi){
  return __builtin_amdgcn_perm(__float_as_uint(hi), __float_as_uint(lo), 0x07060302u);
}

__device__ inline float wave_sum(float v){
  #pragma unroll
  for(int m=32;m>=1;m>>=1) v += __shfl_xor(v,m);
  return v;
}

// ---------------- GroupNorm1 (stats+apply+transpose). x:(BT,C,HW) -> xs:(BT,HW,C)
__global__ __launch_bounds__(256) void gn1_kernel(const float* __restrict__ x,
    const float* __restrict__ w, const float* __restrict__ b, float* __restrict__ xs){
  int g = blockIdx.x, bt = blockIdx.y, tid = threadIdx.x;
  const float* xp = x + ((size_t)bt*512 + g*16)*1024;
  float s=0.f, s2=0.f;
  #pragma unroll
  for(int it=0; it<16; ++it){
    float4 v = *(const float4*)(xp + it*1024 + tid*4);
    s  += v.x+v.y+v.z+v.w;
    s2 += v.x*v.x+v.y*v.y+v.z*v.z+v.w*v.w;
  }
  __shared__ float red[8];
  s = wave_sum(s); s2 = wave_sum(s2);
  int wid = tid>>6;
  if((tid&63)==0){ red[wid*2]=s; red[wid*2+1]=s2; }
  __syncthreads();
  s  = red[0]+red[2]+red[4]+red[6];
  s2 = red[1]+red[3]+red[5]+red[7];
  float mean = s * (1.f/16384.f);
  float var  = s2 * (1.f/16384.f) - mean*mean;
  float rinv = rsqrtf(var + 1e-5f);
  int c = tid & 15, h0 = tid >> 4;
  float sc = w[g*16+c]*rinv;
  float sh = b[g*16+c] - mean*sc;
  const float* xcol = xp + (size_t)c*1024;
  float* op = xs + (size_t)bt*1024*512 + g*16 + c;
  #pragma unroll 4
  for(int it=0; it<64; ++it){
    int hw = h0 + it*16;
    op[(size_t)hw*512] = xcol[hw]*sc + sh;
  }
}

// ---------------- Dual LayerNorm per row: vn (f32+bf16) with lnv params, lnl (bf16)
__global__ __launch_bounds__(256) void ln_dual_kernel(const float* __restrict__ xs,
    const float* __restrict__ lvw, const float* __restrict__ lvb,
    const float* __restrict__ llw, const float* __restrict__ llb,
    float* __restrict__ vn, unsigned short* __restrict__ vnb, unsigned short* __restrict__ lnlb){
  int wid = threadIdx.x>>6, l = threadIdx.x&63;
  size_t row = (size_t)blockIdx.x*4 + wid;
  const float* xp = xs + row*512;
  float4 a = *(const float4*)(xp + l*4);
  float4 c = *(const float4*)(xp + 256 + l*4);
  float s  = a.x+a.y+a.z+a.w + c.x+c.y+c.z+c.w;
  float s2 = a.x*a.x+a.y*a.y+a.z*a.z+a.w*a.w + c.x*c.x+c.y*c.y+c.z*c.z+c.w*c.w;
  s = wave_sum(s); s2 = wave_sum(s2);
  float mean = s*(1.f/512.f);
  float rinv = rsqrtf(s2*(1.f/512.f) - mean*mean + 1e-5f);
  int c0 = l*4, c1 = 256 + l*4;
  float y[8] = {(a.x-mean)*rinv,(a.y-mean)*rinv,(a.z-mean)*rinv,(a.w-mean)*rinv,
                (c.x-mean)*rinv,(c.y-mean)*rinv,(c.z-mean)*rinv,(c.w-mean)*rinv};
  float4 o0, o1;
  o0.x=y[0]*lvw[c0+0]+lvb[c0+0]; o0.y=y[1]*lvw[c0+1]+lvb[c0+1];
  o0.z=y[2]*lvw[c0+2]+lvb[c0+2]; o0.w=y[3]*lvw[c0+3]+lvb[c0+3];
  o1.x=y[4]*lvw[c1+0]+lvb[c1+0]; o1.y=y[5]*lvw[c1+1]+lvb[c1+1];
  o1.z=y[6]*lvw[c1+2]+lvb[c1+2]; o1.w=y[7]*lvw[c1+3]+lvb[c1+3];
  *(float4*)(vn + row*512 + c0) = o0;
  *(float4*)(vn + row*512 + c1) = o1;
  ushort4 h;
  h.x=f2bf(o0.x); h.y=f2bf(o0.y); h.z=f2bf(o0.z); h.w=f2bf(o0.w);
  *(ushort4*)(vnb + row*512 + c0) = h;
  h.x=f2bf(o1.x); h.y=f2bf(o1.y); h.z=f2bf(o1.z); h.w=f2bf(o1.w);
  *(ushort4*)(vnb + row*512 + c1) = h;
  h.x=f2bf(y[0]*llw[c0+0]+llb[c0+0]); h.y=f2bf(y[1]*llw[c0+1]+llb[c0+1]);
  h.z=f2bf(y[2]*llw[c0+2]+llb[c0+2]); h.w=f2bf(y[3]*llw[c0+3]+llb[c0+3]);
  *(ushort4*)(lnlb + row*512 + c0) = h;
  h.x=f2bf(y[4]*llw[c1+0]+llb[c1+0]); h.y=f2bf(y[5]*llw[c1+1]+llb[c1+1]);
  h.z=f2bf(y[6]*llw[c1+2]+llb[c1+2]); h.w=f2bf(y[7]*llw[c1+3]+llb[c1+3]);
  *(ushort4*)(lnlb + row*512 + c1) = h;
}

// ---------------- merged: fused GN2-apply+LayerNorm (ids 0..4095) + context LN (ids 4096+)
// st holds RAW [sum, sum2] per (bt,g) accumulated by the MODE1 GEMM epilogue.
__global__ __launch_bounds__(256) void gn2ctx_kernel(const float* __restrict__ xs2, const float* __restrict__ st,
    const float* __restrict__ gw, const float* __restrict__ gb,
    const float* __restrict__ lw, const float* __restrict__ lb,
    float* __restrict__ vn2, unsigned short* __restrict__ vn2b,
    const float* __restrict__ ctx, const float* __restrict__ clw, const float* __restrict__ clb,
    unsigned short* __restrict__ ctxout){
  int id = blockIdx.x;
  int wid = threadIdx.x>>6, l = threadIdx.x&63;
  int c0 = l*4, c1 = 256 + l*4;
  if(id < 4096){
    size_t row = (size_t)id*4 + wid;
    int bt = (int)(row >> 10);
    const float* xp = xs2 + row*512;
    float4 a = *(const float4*)(xp + l*4);
    float4 c = *(const float4*)(xp + 256 + l*4);
    int g0 = c0>>4, g1 = c1>>4;
    float sm0 = st[(bt*32+g0)*2], sq0 = st[(bt*32+g0)*2+1];
    float sm1 = st[(bt*32+g1)*2], sq1 = st[(bt*32+g1)*2+1];
    float m0 = sm0*(1.f/16384.f);
    float r0 = rsqrtf(sq0*(1.f/16384.f) - m0*m0 + 1e-5f);
    float m1 = sm1*(1.f/16384.f);
    float r1 = rsqrtf(sq1*(1.f/16384.f) - m1*m1 + 1e-5f);
    float y[8];
    y[0]=(a.x-m0)*r0*gw[c0+0]+gb[c0+0]; y[1]=(a.y-m0)*r0*gw[c0+1]+gb[c0+1];
    y[2]=(a.z-m0)*r0*gw[c0+2]+gb[c0+2]; y[3]=(a.w-m0)*r0*gw[c0+3]+gb[c0+3];
    y[4]=(c.x-m1)*r1*gw[c1+0]+gb[c1+0]; y[5]=(c.y-m1)*r1*gw[c1+1]+gb[c1+1];
    y[6]=(c.z-m1)*r1*gw[c1+2]+gb[c1+2]; y[7]=(c.w-m1)*r1*gw[c1+3]+gb[c1+3];
    float s=0.f, s2=0.f;
    #pragma unroll
    for(int i=0;i<8;++i){ s += y[i]; s2 += y[i]*y[i]; }
    s = wave_sum(s); s2 = wave_sum(s2);
    float mean = s*(1.f/512.f);
    float rinv = rsqrtf(s2*(1.f/512.f) - mean*mean + 1e-5f);
    float4 o0, o1;
    o0.x=(y[0]-mean)*rinv*lw[c0+0]+lb[c0+0]; o0.y=(y[1]-mean)*rinv*lw[c0+1]+lb[c0+1];
    o0.z=(y[2]-mean)*rinv*lw[c0+2]+lb[c0+2]; o0.w=(y[3]-mean)*rinv*lw[c0+3]+lb[c0+3];
    o1.x=(y[4]-mean)*rinv*lw[c1+0]+lb[c1+0]; o1.y=(y[5]-mean)*rinv*lw[c1+1]+lb[c1+1];
    o1.z=(y[6]-mean)*rinv*lw[c1+2]+lb[c1+2]; o1.w=(y[7]-mean)*rinv*lw[c1+3]+lb[c1+3];
    *(float4*)(vn2 + row*512 + c0) = o0;
    *(float4*)(vn2 + row*512 + c1) = o1;
    ushort4 h;
    h.x=f2bf(o0.x); h.y=f2bf(o0.y); h.z=f2bf(o0.z); h.w=f2bf(o0.w);
    *(ushort4*)(vn2b + row*512 + c0) = h;
    h.x=f2bf(o1.x); h.y=f2bf(o1.y); h.z=f2bf(o1.z); h.w=f2bf(o1.w);
    *(ushort4*)(vn2b + row*512 + c1) = h;
  } else {
    int row = (id-4096)*4 + wid;
    if(row >= 154) return;
    const float* xp = ctx + (size_t)row*512;
    float4 a = *(const float4*)(xp + l*4);
    float4 c = *(const float4*)(xp + 256 + l*4);
    float s  = a.x+a.y+a.z+a.w + c.x+c.y+c.z+c.w;
    float s2 = a.x*a.x+a.y*a.y+a.z*a.z+a.w*a.w + c.x*c.x+c.y*c.y+c.z*c.z+c.w*c.w;
    s = wave_sum(s); s2 = wave_sum(s2);
    float mean = s*(1.f/512.f);
    float rinv = rsqrtf(s2*(1.f/512.f) - mean*mean + 1e-5f);
    ushort4 h;
    h.x=f2bf((a.x-mean)*rinv*clw[c0+0]+clb[c0+0]); h.y=f2bf((a.y-mean)*rinv*clw[c0+1]+clb[c0+1]);
    h.z=f2bf((a.z-mean)*rinv*clw[c0+2]+clb[c0+2]); h.w=f2bf((a.w-mean)*rinv*clw[c0+3]+clb[c0+3]);
    *(ushort4*)(ctxout + (size_t)row*512 + c0) = h;
    h.x=f2bf((c.x-mean)*rinv*clw[c1+0]+clb[c1+0]); h.y=f2bf((c.y-mean)*rinv*clw[c1+1]+clb[c1+1]);
    h.z=f2bf((c.z-mean)*rinv*clw[c1+2]+clb[c1+2]); h.w=f2bf((c.w-mean)*rinv*clw[c1+3]+clb[c1+3]);
    *(ushort4*)(ctxout + (size_t)row*512 + c1) = h;
  }
}

// ---------------- weight fp32 -> bf16 (8 weights of 512x512)
__global__ __launch_bounds__(256) void cvtw_kernel(const float* s0, const float* s1, const float* s2,
    const float* s3, const float* s4, const float* s5, const float* s6, const float* s7,
    unsigned short* __restrict__ dst){
  const float* srcs[8] = {s0,s1,s2,s3,s4,s5,s6,s7};
  int w = blockIdx.y;
  const float* src = srcs[w];
  int i = (blockIdx.x*256 + threadIdx.x)*4;
  float4 v = *(const float4*)(src + i);
  ushort4 h; h.x=f2bf(v.x); h.y=f2bf(v.y); h.z=f2bf(v.z); h.w=f2bf(v.w);
  *(ushort4*)(dst + (size_t)w*262144 + i) = h;
}

// ======== shared GEMM core: 128x128 tile, BK=64, dbuf LDS, counted vmcnt pipeline ========
__device__ inline void gemm_core(const unsigned short* __restrict__ A,
    const unsigned short* __restrict__ W, int M, int m0, int n0,
    unsigned short* Asl, unsigned short* Wsl, floatx4 acc[4][4]){
  int tid = threadIdx.x, l = tid&63, quad = l>>4, ln16 = l&15;
  int wid = tid>>6;
  int wr = wid>>1, wc = wid&1;
  const unsigned short* Ag[4];
  const unsigned short* Wg[4];
  unsigned short* Al[4];
  unsigned short* Wl[4];
  #pragma unroll
  for(int i=0;i<4;++i){
    int s = i*256 + tid;
    int row = s>>3, kg = s&7;
    int kgs = kg ^ (row&7);
    int ar = m0+row; if(ar > M-1) ar = M-1;
    Ag[i] = A + (size_t)ar*512 + kgs*8;
    Wg[i] = W + (size_t)(n0+row)*512 + kgs*8;
    Al[i] = Asl + row*64 + kg*8;
    Wl[i] = Wsl + row*64 + kg*8;
  }
  #pragma unroll
  for(int mf=0;mf<4;++mf)
    #pragma unroll
    for(int nf=0;nf<4;++nf) acc[mf][nf] = (floatx4){0,0,0,0};
  #pragma unroll
  for(int i=0;i<4;++i){ gll16(Ag[i], Al[i]); gll16(Wg[i], Wl[i]); }
  for(int kt=0; kt<8; ++kt){
    int cur = kt&1;
    if(kt<7){
      int k0n = (kt+1)*64, off = (cur^1)*8192;
      #pragma unroll
      for(int i=0;i<4;++i){ gll16(Ag[i]+k0n, Al[i]+off); gll16(Wg[i]+k0n, Wl[i]+off); }
      asm volatile("s_waitcnt vmcnt(8)" ::: "memory");
    } else {
      asm volatile("s_waitcnt vmcnt(0)" ::: "memory");
    }
    __builtin_amdgcn_s_barrier();
    __builtin_amdgcn_sched_barrier(0);
    const unsigned short* Ab = Asl + cur*8192;
    const unsigned short* Wbb = Wsl + cur*8192;
    #pragma unroll
    for(int kk=0; kk<2; ++kk){
      short8 av[4], wv[4];
      #pragma unroll
      for(int mf=0;mf<4;++mf){
        int row = wr*64 + mf*16 + ln16;
        int sread = (kk*4 + quad) ^ (row&7);
        av[mf] = *(const short8*)(Ab + row*64 + sread*8);
      }
      #pragma unroll
      for(int nf=0;nf<4;++nf){
        int row = wc*64 + nf*16 + ln16;
        int sread = (kk*4 + quad) ^ (row&7);
        wv[nf] = *(const short8*)(Wbb + row*64 + sread*8);
      }
      #pragma unroll
      for(int mf=0;mf<4;++mf)
        #pragma unroll
        for(int nf=0;nf<4;++nf)
          acc[mf][nf] = MFMA_BF16(av[mf], wv[nf], acc[mf][nf], 0,0,0);
    }
    if(kt<7){
      __builtin_amdgcn_sched_barrier(0);
      __builtin_amdgcn_s_barrier();
    }
  }
}

// ---------------- standalone GEMM with epilogue modes (MODE 1 and 2 used)
// MODE 1: outf = r1 + r2 + gamma*(acc+bias); group sums -> (float*)outb via atomics
// MODE 2: outf[bt,c,hw] = r1 + gamma*(acc+bias)               [transposed f32]
template<int MODE>
__global__ __launch_bounds__(256) void gemm128_kernel(const unsigned short* __restrict__ A,
    const unsigned short* __restrict__ W, const float* __restrict__ bias, int M, float scale,
    unsigned short* __restrict__ outb, float* __restrict__ outf,
    const float* __restrict__ r1, const float* __restrict__ r2, const float* __restrict__ gamma){
  __shared__ unsigned short Asl[2][128*64];
  __shared__ unsigned short Wsl[2][128*64];
  int tid = threadIdx.x, l = tid&63, wid = tid>>6, quad = l>>4, ln16 = l&15;
  int wr = wid>>1, wc = wid&1;
  int m0 = blockIdx.x*128, n0 = blockIdx.y*128;
  floatx4 acc[4][4];
  gemm_core(A, W, M, m0, n0, &Asl[0][0], &Wsl[0][0], acc);
  if(MODE==1){
    float gs[4]={0,0,0,0}, gs2[4]={0,0,0,0};
    #pragma unroll
    for(int mf=0;mf<4;++mf){
      int mb = m0 + wr*64 + mf*16 + quad*4;
      #pragma unroll
      for(int nf=0;nf<4;++nf){
        int col = n0 + wc*64 + nf*16 + ln16;
        float bv = bias[col];
        float gv = gamma[col];
        #pragma unroll
        for(int r=0;r<4;++r){
          size_t ix = (size_t)(mb+r)*512 + col;
          float val = r1[ix] + r2[ix] + gv*(acc[mf][nf][r] + bv);
          outf[ix] = val;
          gs[nf] += val; gs2[nf] += val*val;
        }
      }
    }
    float* stats = (float*)outb;
    int btq = m0 >> 10;
    #pragma unroll
    for(int nf=0;nf<4;++nf){
      float sv  = wave_sum(gs[nf]);
      float sv2 = wave_sum(gs2[nf]);
      if(l==0){
        int g = (n0 + wc*64 + nf*16) >> 4;
        atomicAdd(&stats[(btq*32+g)*2],   sv);
        atomicAdd(&stats[(btq*32+g)*2+1], sv2);
      }
    }
    return;
  }
  #pragma unroll
  for(int mf=0;mf<4;++mf){
    int mb = m0 + wr*64 + mf*16 + quad*4;
    #pragma unroll
    for(int nf=0;nf<4;++nf){
      int col = n0 + wc*64 + nf*16 + ln16;
      float bv = bias[col];
      if(MODE==0){
        #pragma unroll
        for(int r=0;r<4;++r){
          int m = mb + r;
          if(m < M) outb[(size_t)m*512 + col] = f2bf((acc[mf][nf][r] + bv)*scale);
        }
      } else if(MODE==2){
        float gv = gamma[col];
        int bt = mb >> 10;
        int hw0 = mb & 1023;
        float4 ov;
        ov.x = r1[(size_t)(mb+0)*512+col] + gv*(acc[mf][nf][0]+bv);
        ov.y = r1[(size_t)(mb+1)*512+col] + gv*(acc[mf][nf][1]+bv);
        ov.z = r1[(size_t)(mb+2)*512+col] + gv*(acc[mf][nf][2]+bv);
        ov.w = r1[(size_t)(mb+3)*512+col] + gv*(acc[mf][nf][3]+bv);
        *(float4*)(outf + (size_t)bt*524288 + (size_t)col*1024 + hw0) = ov;
      }
    }
  }
}

// ---------------- fused sa Q/K/V projections in ONE launch. grid (128,4,3), z selects:
__global__ __launch_bounds__(256) void gemm_qkv_kernel(
    const unsigned short* __restrict__ Aq, const unsigned short* __restrict__ Akv,
    const unsigned short* __restrict__ Wbase,
    const float* __restrict__ bq, const float* __restrict__ bk, const float* __restrict__ bv,
    float qs,
    unsigned short* __restrict__ outQ, unsigned short* __restrict__ outK, unsigned short* __restrict__ outVT){
  __shared__ unsigned short Asl[2][128*64];
  __shared__ unsigned short Wsl[2][128*64];
  int tid = threadIdx.x, l = tid&63, wid = tid>>6, quad = l>>4, ln16 = l&15;
  int wr = wid>>1, wc = wid&1;
  int z = blockIdx.z;
  int m0 = blockIdx.x*128, n0 = blockIdx.y*128;
  const unsigned short* A = (z==0) ? Aq : Akv;
  const unsigned short* W = Wbase + (size_t)z*262144;
  const float* bias = (z==0) ? bq : ((z==1) ? bk : bv);
  floatx4 acc[4][4];
  gemm_core(A, W, 16384, m0, n0, &Asl[0][0], &Wsl[0][0], acc);
  #pragma unroll
  for(int mf=0;mf<4;++mf){
    int mb = m0 + wr*64 + mf*16 + quad*4;
    #pragma unroll
    for(int nf=0;nf<4;++nf){
      int col = n0 + wc*64 + nf*16 + ln16;
      float bv_ = bias[col];
      if(z==0){
        #pragma unroll
        for(int r=0;r<4;++r)
          outQ[(size_t)(mb+r)*512 + col] = f2bf((acc[mf][nf][r] + bv_)*qs);
      } else if(z==1){
        #pragma unroll
        for(int r=0;r<4;++r)
          outK[(size_t)(mb+r)*512 + col] = f2bf(acc[mf][nf][r] + bv_);
      } else {
        int bf = mb >> 10;
        int hw0 = mb & 1023;
        ushort4 h;
        h.x = f2bf(acc[mf][nf][0]+bv_); h.y = f2bf(acc[mf][nf][1]+bv_);
        h.z = f2bf(acc[mf][nf][2]+bv_); h.w = f2bf(acc[mf][nf][3]+bv_);
        *(ushort4*)(outVT + ((size_t)bf*512 + col)*1024 + hw0) = h;
      }
    }
  }
}

// ---------------- merged ca projections in ONE launch, 1D grid 528:
// ids 0..511:  Qb = bf16((vnb@Wcq^T + cqb)*qs)         [bx=id&127, by=id>>7]
// ids 512+:    j=id-512, z=j>>3: z=0 K2b natural, z=1 V2T scatter [bx=j&1, by=(j>>1)&3]
__global__ __launch_bounds__(256) void gemm_ca2_kernel(
    const unsigned short* __restrict__ Avq, const unsigned short* __restrict__ Actx,
    const unsigned short* __restrict__ Wbase,   // Wb + 4*262144 (ca_qw, ca_kw, ca_vw)
    const float* __restrict__ bq, const float* __restrict__ bk, const float* __restrict__ bv,
    float qs,
    unsigned short* __restrict__ outQ, unsigned short* __restrict__ outK2, unsigned short* __restrict__ outV2T){
  __shared__ unsigned short Asl[2][128*64];
  __shared__ unsigned short Wsl[2][128*64];
  int tid = threadIdx.x, l = tid&63, wid = tid>>6, quad = l>>4, ln16 = l&15;
  int wr = wid>>1, wc = wid&1;
  int id = blockIdx.x;
  floatx4 acc[4][4];
  if(id < 512){
    int m0 = (id & 127)*128, n0 = (id >> 7)*128;
    gemm_core(Avq, Wbase, 16384, m0, n0, &Asl[0][0], &Wsl[0][0], acc);
    #pragma unroll
    for(int mf=0;mf<4;++mf){
      int mb = m0 + wr*64 + mf*16 + quad*4;
      #pragma unroll
      for(int nf=0;nf<4;++nf){
        int col = n0 + wc*64 + nf*16 + ln16;
        float bv_ = bq[col];
        #pragma unroll
        for(int r=0;r<4;++r)
          outQ[(size_t)(mb+r)*512 + col] = f2bf((acc[mf][nf][r] + bv_)*qs);
      }
    }
  } else {
    int j = id - 512;
    int z = j >> 3;
    int m0 = (j & 1)*128, n0 = ((j>>1)&3)*128;
    gemm_core(Actx, Wbase + (size_t)(1+z)*262144, 154, m0, n0, &Asl[0][0], &Wsl[0][0], acc);
    const float* bias = (z==0) ? bk : bv;
    #pragma unroll
    for(int mf=0;mf<4;++mf){
      int mb = m0 + wr*64 + mf*16 + quad*4;
      #pragma unroll
      for(int nf=0;nf<4;++nf){
        int col = n0 + wc*64 + nf*16 + ln16;
        float bv_ = bias[col];
        #pragma unroll
        for(int r=0;r<4;++r){
          int m = mb + r;
          if(m < 154){
            if(z==0){
              outK2[(size_t)m*512 + col] = f2bf(acc[mf][nf][r] + bv_);
            } else {
              int cb = (m >= 77) ? 1 : 0;
              int key = m - 77*cb;
              outV2T[((size_t)cb*512 + col)*128 + key] = f2bf(acc[mf][nf][r] + bv_);
            }
          }
        }
      }
    }
  }
}

// ---------------- spatial flash attention v7 (proven best): 64 q/wave, double-buffered
// K/V LDS via register staging, 1 barrier/chunk, prefetch issued before barrier.
// grid 1D 512: id = qt*128 + head*16 + bz, qt in 0..3 (256 q rows per block).
__global__ __launch_bounds__(256, 2) void attn_sp_kernel(const unsigned short* __restrict__ Q,
    const unsigned short* __restrict__ K, const unsigned short* __restrict__ VT,
    unsigned short* __restrict__ O){
  int id = blockIdx.x;
  int hb = id & 127, qt = id >> 7;
  int head = hb >> 4, bz = hb & 15;
  int b = bz >> 3, idx = bz & 7;
  int tid = threadIdx.x, wid = tid>>6, l = tid&63, quad = l>>4, ln16 = l&15;
  __shared__ unsigned short vt[2][64*72];     // [buf][dim][key]
  __shared__ unsigned short kt[2][64*72];     // [buf][key][dim]
  size_t qbase = (size_t)bz*1024 + qt*256 + wid*64 + ln16;
  short8 qb[4][2];
  #pragma unroll
  for(int grp=0;grp<4;++grp){
    const unsigned short* qp = Q + (qbase + grp*16)*512 + head*64 + quad*8;
    qb[grp][0] = *(const short8*)(qp);
    qb[grp][1] = *(const short8*)(qp + 32);
  }
  floatx4 o[4][4];
  #pragma unroll
  for(int g=0;g<4;++g)
    #pragma unroll
    for(int d=0;d<4;++d) o[g][d] = (floatx4){0,0,0,0};
  float lr[4] = {0.f,0.f,0.f,0.f};
  int nch = idx ? 32 : 16;
  int f0  = idx ? (idx-1) : 0;
  int sr = tid>>2, sc0 = (tid&3)*16;
  short8 pv0, pv1, pk0, pk1;
  {
    const unsigned short* vp = VT + (((size_t)(b*8+f0)*512) + head*64 + sr)*1024 + sc0;
    pv0 = *(const short8*)(vp); pv1 = *(const short8*)(vp + 8);
    const unsigned short* kp = K + (((size_t)(b*8+f0))*1024 + sr)*512 + head*64 + sc0;
    pk0 = *(const short8*)(kp); pk1 = *(const short8*)(kp + 8);
  }
  for(int ch=0; ch<nch; ++ch){
    int bf_ = ch & 1;
    *(short8*)(&vt[bf_][0] + sr*72 + sc0)     = pv0;
    *(short8*)(&vt[bf_][0] + sr*72 + sc0 + 8) = pv1;
    *(short8*)(&kt[bf_][0] + sr*72 + sc0)     = pk0;
    *(short8*)(&kt[bf_][0] + sr*72 + sc0 + 8) = pk1;
    if(ch+1 < nch){
      int f = f0 + ((ch+1)>>4);
      int kk0 = ((ch+1)&15)*64;
      const unsigned short* vp = VT + (((size_t)(b*8+f)*512) + head*64 + sr)*1024 + kk0 + sc0;
      pv0 = *(const short8*)(vp); pv1 = *(const short8*)(vp + 8);
      const unsigned short* kp = K + (((size_t)(b*8+f))*1024 + kk0 + sr)*512 + head*64 + sc0;
      pk0 = *(const short8*)(kp); pk1 = *(const short8*)(kp + 8);
    }
    __syncthreads();
    #pragma unroll
    for(int g=0; g<4; ++g){
      const unsigned short* kr = &kt[bf_][0] + (g*16+ln16)*72 + quad*8;
      short8 k0 = *(const short8*)(kr);
      short8 k1 = *(const short8*)(kr + 32);
      short4v va[4];
      #pragma unroll
      for(int dc=0; dc<4; ++dc)
        va[dc] = *(const short4v*)(&vt[bf_][0] + (dc*16+ln16)*72 + g*16 + quad*4);
      #pragma unroll
      for(int grp=0; grp<4; ++grp){
        floatx4 s = {0,0,0,0};
        s = MFMA_BF16(k0, qb[grp][0], s, 0,0,0);
        s = MFMA_BF16(k1, qb[grp][1], s, 0,0,0);
        float p0 = __builtin_amdgcn_exp2f(s[0]);
        float p1 = __builtin_amdgcn_exp2f(s[1]);
        float p2 = __builtin_amdgcn_exp2f(s[2]);
        float p3 = __builtin_amdgcn_exp2f(s[3]);
        lr[grp] += (p0+p1)+(p2+p3);
        uint2 pu; pu.x = pack_bf(p0,p1); pu.y = pack_bf(p2,p3);
        short4v pb = __builtin_bit_cast(short4v, pu);
        #pragma unroll
        for(int dc=0; dc<4; ++dc)
          o[grp][dc] = MFMA16(va[dc], pb, o[grp][dc]);
      }
    }
  }
  #pragma unroll
  for(int grp=0; grp<4; ++grp){
    float lt = lr[grp];
    lt += __shfl_xor(lt, 16); lt += __shfl_xor(lt, 32);
    float inv = __builtin_amdgcn_rcpf(lt);
    size_t orow = qbase + grp*16;
    unsigned short* op = O + orow*512 + head*64 + quad*4;
    #pragma unroll
    for(int dc=0; dc<4; ++dc){
      uint2 pk;
      pk.x = pack_bf(o[grp][dc][0]*inv, o[grp][dc][1]*inv);
      pk.y = pack_bf(o[grp][dc][2]*inv, o[grp][dc][3]*inv);
      *(uint2*)(op + dc*16) = pk;
    }
  }
}

// ---------------- cross attention v8: 64 q/wave (attn_sp-v7 structure), 77 keys
// (2 chunks of 64, masked), dbuf, prefetch before barrier. grid 1D 512.
__global__ __launch_bounds__(256, 2) void attn_ca_kernel(const unsigned short* __restrict__ Q,
    const unsigned short* __restrict__ K2, const unsigned short* __restrict__ V2T,
    unsigned short* __restrict__ O){
  int id = blockIdx.x;
  int hb = id & 127, qt = id >> 7;
  int head = hb >> 4, bt = hb & 15;
  int cb = bt & 1;
  int tid = threadIdx.x, wid = tid>>6, l = tid&63, quad = l>>4, ln16 = l&15;
  __shared__ unsigned short vt[2][64*72];
  __shared__ unsigned short kt[2][64*72];
  size_t qbase = (size_t)bt*1024 + qt*256 + wid*64 + ln16;
  short8 qb[4][2];
  #pragma unroll
  for(int grp=0;grp<4;++grp){
    const unsigned short* qp = Q + (qbase + grp*16)*512 + head*64 + quad*8;
    qb[grp][0] = *(const short8*)(qp);
    qb[grp][1] = *(const short8*)(qp + 32);
  }
  floatx4 o[4][4];
  #pragma unroll
  for(int g=0;g<4;++g)
    #pragma unroll
    for(int d=0;d<4;++d) o[g][d] = (floatx4){0,0,0,0};
  float lr[4] = {0.f,0.f,0.f,0.f};
  int sr = tid>>2, sc0 = (tid&3)*16;
  short8 pv0, pv1, pk0, pk1;
  {
    const unsigned short* vp = V2T + (((size_t)cb*512) + head*64 + sr)*128 + sc0;
    pv0 = *(const short8*)(vp); pv1 = *(const short8*)(vp + 8);
    const unsigned short* kp = K2 + ((size_t)cb*77 + sr)*512 + head*64 + sc0;
    pk0 = *(const short8*)(kp); pk1 = *(const short8*)(kp + 8);
  }
  for(int ch=0; ch<2; ++ch){
    int bf_ = ch & 1;
    int kk0 = ch*64;
    *(short8*)(&vt[bf_][0] + sr*72 + sc0)     = pv0;
    *(short8*)(&vt[bf_][0] + sr*72 + sc0 + 8) = pv1;
    *(short8*)(&kt[bf_][0] + sr*72 + sc0)     = pk0;
    *(short8*)(&kt[bf_][0] + sr*72 + sc0 + 8) = pk1;
    if(ch == 0){
      const unsigned short* vp = V2T + (((size_t)cb*512) + head*64 + sr)*128 + 64 + sc0;
      pv0 = *(const short8*)(vp); pv1 = *(const short8*)(vp + 8);
      const unsigned short* kp = K2 + ((size_t)cb*77 + 64 + sr)*512 + head*64 + sc0;
      pk0 = *(const short8*)(kp); pk1 = *(const short8*)(kp + 8);
    }
    __syncthreads();
    #pragma unroll
    for(int g=0; g<4; ++g){
      int kg = kk0 + g*16 + quad*4;
      const unsigned short* kr = &kt[bf_][0] + (g*16+ln16)*72 + quad*8;
      short8 k0 = *(const short8*)(kr);
      short8 k1 = *(const short8*)(kr + 32);
      short4v va[4];
      #pragma unroll
      for(int dc=0; dc<4; ++dc)
        va[dc] = *(const short4v*)(&vt[bf_][0] + (dc*16+ln16)*72 + g*16 + quad*4);
      #pragma unroll
      for(int grp=0; grp<4; ++grp){
        floatx4 s = {0,0,0,0};
        s = MFMA_BF16(k0, qb[grp][0], s, 0,0,0);
        s = MFMA_BF16(k1, qb[grp][1], s, 0,0,0);
        float p0 = (kg+0 < 77) ? __builtin_amdgcn_exp2f(s[0]) : 0.f;
        float p1 = (kg+1 < 77) ? __builtin_amdgcn_exp2f(s[1]) : 0.f;
        float p2 = (kg+2 < 77) ? __builtin_amdgcn_exp2f(s[2]) : 0.f;
        float p3 = (kg+3 < 77) ? __builtin_amdgcn_exp2f(s[3]) : 0.f;
        lr[grp] += (p0+p1)+(p2+p3);
        uint2 pu; pu.x = pack_bf(p0,p1); pu.y = pack_bf(p2,p3);
        short4v pb = __builtin_bit_cast(short4v, pu);
        #pragma unroll
        for(int dc=0; dc<4; ++dc)
          o[grp][dc] = MFMA16(va[dc], pb, o[grp][dc]);
      }
    }
  }
  #pragma unroll
  for(int grp=0; grp<4; ++grp){
    float lt = lr[grp];
    lt += __shfl_xor(lt, 16); lt += __shfl_xor(lt, 32);
    float inv = __builtin_amdgcn_rcpf(lt);
    size_t orow = qbase + grp*16;
    unsigned short* op = O + orow*512 + head*64 + quad*4;
    #pragma unroll
    for(int dc=0; dc<4; ++dc){
      uint2 pk;
      pk.x = pack_bf(o[grp][dc][0]*inv, o[grp][dc][1]*inv);
      pk.y = pack_bf(o[grp][dc][2]*inv, o[grp][dc][3]*inv);
      *(uint2*)(op + dc*16) = pk;
    }
  }
}

extern "C" void kernel_launch(void* const* d_in, const int* in_sizes, int n_in,
                              void* d_out, int out_size, void* d_ws, size_t ws_size,
                              hipStream_t stream) {
  const float* x        = (const float*)d_in[0];
  const float* ctx      = (const float*)d_in[1];
  const float* gn1w     = (const float*)d_in[2];
  const float* gn1b     = (const float*)d_in[3];
  const float* gn2w     = (const float*)d_in[4];
  const float* gn2b     = (const float*)d_in[5];
  const float* sa_lnv_w = (const float*)d_in[6];
  const float* sa_lnv_b = (const float*)d_in[7];
  const float* sa_lnl_w = (const float*)d_in[8];
  const float* sa_lnl_b = (const float*)d_in[9];
  const float* sa_qw    = (const float*)d_in[10];
  const float* sa_qb    = (const float*)d_in[11];
  const float* sa_kw    = (const float*)d_in[12];
  const float* sa_kb    = (const float*)d_in[13];
  const float* sa_vw    = (const float*)d_in[14];
  const float* sa_vb    = (const float*)d_in[15];
  const float* sa_ow    = (const float*)d_in[16];
  const float* sa_ob    = (const float*)d_in[17];
  const float* sa_gamma = (const float*)d_in[18];
  const float* ca_lnv_w = (const float*)d_in[19];
  const float* ca_lnv_b = (const float*)d_in[20];
  const float* ca_lnl_w = (const float*)d_in[21];
  const float* ca_lnl_b = (const float*)d_in[22];
  const float* ca_qw    = (const float*)d_in[23];
  const float* ca_qb    = (const float*)d_in[24];
  const float* ca_kw    = (const float*)d_in[25];
  const float* ca_kb    = (const float*)d_in[26];
  const float* ca_vw    = (const float*)d_in[27];
  const float* ca_vb    = (const float*)d_in[28];
  const float* ca_ow    = (const float*)d_in[29];
  const float* ca_ob    = (const float*)d_in[30];
  const float* ca_gamma = (const float*)d_in[31];

  const size_t BIGF = (size_t)16384*512*4;   // 33.55 MB
  const size_t BIGH = (size_t)16384*512*2;   // 16.78 MB
  char* w8 = (char*)d_ws;
  float*          xs   = (float*)(w8);
  float*          vn   = (float*)(w8 + BIGF);                  // later reused as vn2
  unsigned short* vnb  = (unsigned short*)(w8 + 2*BIGF);       // later vn2b
  unsigned short* lnlb = (unsigned short*)(w8 + 2*BIGF + 1*BIGH);
  unsigned short* Qb   = (unsigned short*)(w8 + 2*BIGF + 2*BIGH);  // later Q2
  unsigned short* Kb   = (unsigned short*)(w8 + 2*BIGF + 3*BIGH);
  unsigned short* VTb  = (unsigned short*)(w8 + 2*BIGF + 4*BIGH);  // V transposed [(bf)*512+c][1024]
  unsigned short* Ob   = (unsigned short*)(w8 + 2*BIGF + 5*BIGH);
  char* small = w8 + 2*BIGF + 6*BIGH;
  float*          st   = (float*)(small);                 // 4 KB raw [sum,sum2] per (bt,g)
  unsigned short* ctxb = (unsigned short*)(small + 4096); // 154*512*2
  unsigned short* Wb   = (unsigned short*)(small + 4096 + 157696); // 8 x 512x512 bf16
  // K2b / V2T alias the xs buffer (xs is dead after the sa O-projection)
  unsigned short* K2b  = (unsigned short*)(w8);                     // rows 0..153 valid
  unsigned short* V2T  = (unsigned short*)(w8 + 1048576);           // 2*512*128 bf16
  float* xs2 = (float*)d_out;   // d_out doubles as xs2; fully overwritten by final GEMM

  const float QS = 0.125f * LOG2E;   // fold softmax log2e into Q scale (exp2 path)

  (void)hipMemsetAsync(st, 0, 4096, stream);   // early: st untouched until MODE1 GEMM
  cvtw_kernel<<<dim3(256,8),256,0,stream>>>(sa_qw, sa_kw, sa_vw, sa_ow, ca_qw, ca_kw, ca_vw, ca_ow, Wb);
  gn1_kernel<<<dim3(32,16),256,0,stream>>>(x, gn1w, gn1b, xs);
  ln_dual_kernel<<<4096,256,0,stream>>>(xs, sa_lnv_w, sa_lnv_b, sa_lnl_w, sa_lnl_b, vn, vnb, lnlb);
  gemm_qkv_kernel<<<dim3(128,4,3),256,0,stream>>>(vnb, lnlb, Wb, sa_qb, sa_kb, sa_vb, QS, Qb, Kb, VTb);
  attn_sp_kernel<<<512,256,0,stream>>>(Qb, Kb, VTb, Ob);
  gemm128_kernel<1><<<dim3(128,4),256,0,stream>>>(Ob, Wb+3*262144, sa_ob, 16384, 1.0f, (unsigned short*)st, xs2, xs, vn, sa_gamma);
  (void)hipMemsetAsync(V2T, 0, (size_t)2*512*128*2, stream);   // xs dead now
  gn2ctx_kernel<<<4135,256,0,stream>>>(xs2, st, gn2w, gn2b, ca_lnv_w, ca_lnv_b, vn, vnb,
                                       ctx, ca_lnl_w, ca_lnl_b, ctxb);
  gemm_ca2_kernel<<<528,256,0,stream>>>(vnb, ctxb, Wb+4*262144, ca_qb, ca_kb, ca_vb, QS, Qb, K2b, V2T);
  attn_ca_kernel<<<512,256,0,stream>>>(Qb, K2b, V2T, Ob);
  gemm128_kernel<2><<<dim3(128,4),256,0,stream>>>(Ob, Wb+7*262144, ca_ob, 16384, 1.0f, nullptr, (float*)d_out, vn, nullptr, ca_gamma);
}